// Round 2
// baseline (2806.883 us; speedup 1.0000x reference)
//
#include <hip/hip_runtime.h>
#include <hip/hip_bf16.h>
#include <math.h>

typedef __hip_bfloat16 bf16;

#define D_MODEL 1024
#define D_INNER 2048
#define N_HEADS 8
#define D_STATE 64
#define CHUNK 64
#define HEAD_DIM 256
#define NCHUNK 4
#define BATCH 32
#define SEQ 256
#define ROWS (BATCH*SEQ)          // 8192
#define PROJ_N 5128
#define O1 D_INNER                // 2048
#define O2 (2*D_INNER)            // 4096
#define O3 (O2 + N_HEADS*D_STATE) // 4608
#define O4 (O3 + N_HEADS*D_STATE) // 5120
#define EPSF 1.1920929e-07f

__device__ __forceinline__ float silu_f(float x){ return x / (1.0f + expf(-x)); }
__device__ __forceinline__ float b2f(bf16 v){ return __bfloat162float(v); }
__device__ __forceinline__ bf16  f2b(float v){ return __float2bfloat16(v); }

__device__ __forceinline__ float block_sum_256(float v){
    __shared__ float sm[4];
    #pragma unroll
    for (int o = 32; o > 0; o >>= 1) v += __shfl_down(v, o, 64);
    int lane = threadIdx.x & 63, w = threadIdx.x >> 6;
    if (lane == 0) sm[w] = v;
    __syncthreads();
    return sm[0] + sm[1] + sm[2] + sm[3];
}

// ---------------- RMSNorm (input) -> hn (f32, stored in d_out scratch) ----------------
__global__ __launch_bounds__(256) void k_rms_in(const float* __restrict__ x,
                                                const float* __restrict__ g,
                                                float* __restrict__ out){
    int row = blockIdx.x, t = threadIdx.x;
    const float4* xr = (const float4*)(x + (size_t)row * D_MODEL);
    float4 v = xr[t];
    float ss = v.x*v.x + v.y*v.y + v.z*v.z + v.w*v.w;
    ss = block_sum_256(ss);
    float sc = rsqrtf(ss * (1.0f/(float)D_MODEL) + EPSF);
    float4 gv = ((const float4*)g)[t];
    float4 o;
    o.x = v.x*sc*gv.x; o.y = v.y*sc*gv.y; o.z = v.z*sc*gv.z; o.w = v.w*sc*gv.w;
    ((float4*)(out + (size_t)row * D_MODEL))[t] = o;
}

// ---------------- GEMM1: [8192x1024] x [5128x1024]^T, segmented stores ----------------
__global__ __launch_bounds__(256) void k_gemm1(const float* __restrict__ A,
                                               const float* __restrict__ B,
                                               bf16* __restrict__ z,
                                               bf16* __restrict__ xp,
                                               float* __restrict__ Bc,
                                               float* __restrict__ Cc,
                                               float* __restrict__ dtr){
    __shared__ float As[16][65];
    __shared__ float Bs[16][65];
    int bn = blockIdx.x * 64, bm = blockIdx.y * 64;
    int tid = threadIdx.x;
    int tr = tid >> 4, tc = tid & 15;
    float acc[4][4] = {};
    for (int k0 = 0; k0 < D_MODEL; k0 += 16){
        #pragma unroll
        for (int i = 0; i < 4; i++){
            int idx = tid + i*256;
            int r = idx >> 4, c = idx & 15;
            As[c][r] = A[(size_t)(bm + r) * D_MODEL + k0 + c];
            int rn = bn + r;
            Bs[c][r] = (rn < PROJ_N) ? B[(size_t)rn * D_MODEL + k0 + c] : 0.0f;
        }
        __syncthreads();
        #pragma unroll
        for (int kk = 0; kk < 16; kk++){
            float a0 = As[kk][tr*4+0], a1 = As[kk][tr*4+1];
            float a2 = As[kk][tr*4+2], a3 = As[kk][tr*4+3];
            float b0 = Bs[kk][tc*4+0], b1 = Bs[kk][tc*4+1];
            float b2 = Bs[kk][tc*4+2], b3 = Bs[kk][tc*4+3];
            acc[0][0] += a0*b0; acc[0][1] += a0*b1; acc[0][2] += a0*b2; acc[0][3] += a0*b3;
            acc[1][0] += a1*b0; acc[1][1] += a1*b1; acc[1][2] += a1*b2; acc[1][3] += a1*b3;
            acc[2][0] += a2*b0; acc[2][1] += a2*b1; acc[2][2] += a2*b2; acc[2][3] += a2*b3;
            acc[3][0] += a3*b0; acc[3][1] += a3*b1; acc[3][2] += a3*b2; acc[3][3] += a3*b3;
        }
        __syncthreads();
    }
    #pragma unroll
    for (int i = 0; i < 4; i++){
        int r = bm + tr*4 + i;
        #pragma unroll
        for (int j = 0; j < 4; j++){
            int c = bn + tc*4 + j;
            float v = acc[i][j];
            if (c < O1)            z [(size_t)r * D_INNER + c]        = f2b(v);
            else if (c < O2)       xp[(size_t)r * D_INNER + (c - O1)] = f2b(v);
            else if (c < O3)       Bc[(size_t)r * 512 + (c - O2)]     = v;
            else if (c < O4)       Cc[(size_t)r * 512 + (c - O3)]     = v;
            else if (c < PROJ_N)   dtr[(size_t)r * 8 + (c - O4)]      = v;
        }
    }
}

// ---------------- depthwise causal conv(4) + SiLU (bf16 in/out) ----------------
__global__ __launch_bounds__(256) void k_conv_silu(const bf16* __restrict__ xp,
                                                   const float* __restrict__ cw,
                                                   const float* __restrict__ cb,
                                                   bf16* __restrict__ xout){
    int b = blockIdx.x;
    int c = blockIdx.y * 256 + threadIdx.x;
    float w0 = cw[c*4+0], w1 = cw[c*4+1], w2 = cw[c*4+2], w3 = cw[c*4+3];
    float bias = cb[c];
    const bf16* ib = xp + (size_t)b * SEQ * D_INNER + c;
    bf16* ob = xout + (size_t)b * SEQ * D_INNER + c;
    float x0 = 0.f, x1 = 0.f, x2 = 0.f;
    for (int s = 0; s < SEQ; s++){
        float x3 = b2f(ib[(size_t)s * D_INNER]);
        float a = x0*w0 + x1*w1 + x2*w2 + x3*w3 + bias;
        ob[(size_t)s * D_INNER] = f2b(silu_f(a));
        x0 = x1; x1 = x2; x2 = x3;
    }
}

// ---------------- precompute Wm (8x8), bm (8), A (8) ----------------
__global__ __launch_bounds__(64) void k_prep(const float* __restrict__ W_dt,
                                             const float* __restrict__ b_dt,
                                             const float* __restrict__ A_log,
                                             float* __restrict__ misc){
    int t = threadIdx.x;
    int h = t >> 3, k = t & 7;
    float s = 0.f;
    for (int d = 0; d < HEAD_DIM; d++) s += W_dt[(size_t)(h*HEAD_DIM + d) * N_HEADS + k];
    misc[t] = s * (1.0f/(float)HEAD_DIM);
    if (t < 8){
        float sb = 0.f;
        for (int d = 0; d < HEAD_DIM; d++) sb += b_dt[t*HEAD_DIM + d];
        misc[64 + t] = sb * (1.0f/(float)HEAD_DIM);
        misc[72 + t] = -expf(A_log[t]);
    }
}

// ---------------- dt_h -> logA cumsum (lcs) + tdec ----------------
__global__ __launch_bounds__(64) void k_dt_lcs(const float* __restrict__ dtr,
                                               const float* __restrict__ misc,
                                               float* __restrict__ lcs,
                                               float* __restrict__ tdec){
    __shared__ float sm[80];
    __shared__ float la[CHUNK][N_HEADS];
    int bc = blockIdx.x;
    int l = threadIdx.x;
    for (int i = l; i < 80; i += 64) sm[i] = misc[i];
    __syncthreads();
    const float* dr = dtr + (size_t)(bc*CHUNK + l) * 8;
    float d0 = dr[0], d1 = dr[1], d2 = dr[2], d3 = dr[3];
    float d4 = dr[4], d5 = dr[5], d6 = dr[6], d7 = dr[7];
    #pragma unroll
    for (int h = 0; h < 8; h++){
        float dt = sm[64+h]
                 + d0*sm[h*8+0] + d1*sm[h*8+1] + d2*sm[h*8+2] + d3*sm[h*8+3]
                 + d4*sm[h*8+4] + d5*sm[h*8+5] + d6*sm[h*8+6] + d7*sm[h*8+7];
        float sp = (dt > 20.f) ? dt : log1pf(expf(dt));
        la[l][h] = sp * sm[72+h];
    }
    __syncthreads();
    float out[8];
    #pragma unroll
    for (int h = 0; h < 8; h++) out[h] = 0.f;
    for (int l2 = 0; l2 <= l; l2++){
        #pragma unroll
        for (int h = 0; h < 8; h++) out[h] += la[l2][h];
    }
    float* lo = lcs + (size_t)(bc*CHUNK + l) * N_HEADS;
    #pragma unroll
    for (int h = 0; h < 8; h++) lo[h] = out[h];
    if (l == 63){
        #pragma unroll
        for (int h = 0; h < 8; h++) tdec[bc*N_HEADS + h] = expf(out[h]);
    }
}

// ---------------- states[d][n] = sum_s Mlast[s]*B[s,n]*x[s,d] (bf16 out) ----------------
__global__ __launch_bounds__(256) void k_states(const float* __restrict__ Bc,
                                                const bf16* __restrict__ x,
                                                const float* __restrict__ lcs,
                                                bf16* __restrict__ states){
    int blk = blockIdx.x;       // (b*4+c)*8 + h
    int h = blk & 7, bc = blk >> 3;
    __shared__ float Bs[CHUNK][D_STATE+1];
    __shared__ float ml[CHUNK];
    int tid = threadIdx.x;
    #pragma unroll
    for (int i = 0; i < 16; i++){
        int idx = tid + i*256;
        int s = idx >> 6, n = idx & 63;
        Bs[s][n] = Bc[(size_t)(bc*CHUNK + s) * 512 + h*D_STATE + n];
    }
    if (tid < 64){
        float l63 = lcs[(size_t)(bc*CHUNK + 63) * N_HEADS + h];
        ml[tid] = expf(l63 - lcs[(size_t)(bc*CHUNK + tid) * N_HEADS + h]);
    }
    __syncthreads();
    int d = tid;
    float xw[64];
    #pragma unroll
    for (int s = 0; s < 64; s++)
        xw[s] = b2f(x[(size_t)(bc*CHUNK + s) * D_INNER + h*HEAD_DIM + d]) * ml[s];
    bf16* so = states + (size_t)blk * (HEAD_DIM*D_STATE) + (size_t)d * D_STATE;
    for (int n = 0; n < 64; n++){
        float a = 0.f;
        #pragma unroll
        for (int s = 0; s < 64; s++) a += xw[s] * Bs[s][n];
        so[n] = f2b(a);
    }
}

// ---------------- 4-chunk sequential scan, in place: states -> h0 ----------------
__global__ __launch_bounds__(256) void k_scan(bf16* __restrict__ states,
                                              const float* __restrict__ tdec){
    int idx = blockIdx.x * 256 + threadIdx.x;
    int dn = idx & 16383;
    int bh = idx >> 14;
    int b = bh >> 3, h = bh & 7;
    float carry = 0.f;
    #pragma unroll
    for (int c = 0; c < NCHUNK; c++){
        size_t s = ((size_t)((b*NCHUNK + c)*N_HEADS + h)) * 16384 + dn;
        float st = b2f(states[s]);
        states[s] = f2b(carry);
        carry = tdec[(b*NCHUNK + c)*N_HEADS + h] * carry + st;
    }
}

// ---------------- intra + inter + D-term -> y (in place over x) ----------------
__global__ __launch_bounds__(256) void k_intra_inter(const float* __restrict__ Bc,
                                                     const float* __restrict__ Cc,
                                                     const float* __restrict__ lcs,
                                                     const bf16* __restrict__ h0,
                                                     const float* __restrict__ Dv,
                                                     bf16* __restrict__ xy){
    int blk = blockIdx.x;       // (b*4+c)*8 + h
    int h = blk & 7, bc = blk >> 3;
    __shared__ float Cs[CHUNK][D_STATE+1];
    __shared__ float Bs[CHUNK][D_STATE+1];
    __shared__ float GMT[CHUNK][CHUNK+1];   // GMT[s][l]
    __shared__ float el[CHUNK];
    int tid = threadIdx.x;
    #pragma unroll
    for (int i = 0; i < 16; i++){
        int idx = tid + i*256;
        int s = idx >> 6, n = idx & 63;
        size_t rb = (size_t)(bc*CHUNK + s) * 512 + h*D_STATE;
        Bs[s][n] = Bc[rb + n];
        Cs[s][n] = Cc[rb + n];
    }
    if (tid < 64) el[tid] = lcs[(size_t)(bc*CHUNK + tid) * N_HEADS + h];
    __syncthreads();
    #pragma unroll
    for (int i = 0; i < 16; i++){
        int idx = tid + i*256;
        int l = idx >> 6, s = idx & 63;
        float g = 0.f;
        if (s <= l){
            #pragma unroll
            for (int n = 0; n < 64; n++) g += Cs[l][n] * Bs[s][n];
            g *= expf(el[l] - el[s]);
        }
        GMT[s][l] = g;
    }
    __syncthreads();
    int d = tid;
    float acc[64];
    #pragma unroll
    for (int l = 0; l < 64; l++) acc[l] = 0.f;
    const bf16* h0r = h0 + (size_t)blk * 16384 + (size_t)d * 64;
    for (int n = 0; n < 64; n++){
        float hn = b2f(h0r[n]);
        #pragma unroll
        for (int l = 0; l < 64; l++) acc[l] += Cs[l][n] * hn;
    }
    #pragma unroll
    for (int l = 0; l < 64; l++) acc[l] *= expf(el[l]);
    bf16* xb = xy + (size_t)(bc*CHUNK) * D_INNER + h*HEAD_DIM + d;
    for (int s = 0; s < 64; s++){
        float xv = b2f(xb[(size_t)s * D_INNER]);
        #pragma unroll
        for (int l = 0; l < 64; l++) acc[l] += GMT[s][l] * xv;
    }
    float Dh = Dv[h];
    #pragma unroll
    for (int l = 0; l < 64; l++){
        float xv = b2f(xb[(size_t)l * D_INNER]);
        xb[(size_t)l * D_INNER] = f2b(acc[l] + xv * Dh);
    }
}

// ---------------- gate with silu(z) + RMSNorm (output) -> yn bf16 ----------------
__global__ __launch_bounds__(256) void k_gate_rms(const bf16* __restrict__ y,
                                                  const bf16* __restrict__ z,
                                                  const float* __restrict__ g,
                                                  bf16* __restrict__ yn){
    int row = blockIdx.x, t = threadIdx.x;
    union { uint4 u; bf16 b[8]; } yv, zv, ov;
    yv.u = ((const uint4*)(y + (size_t)row * D_INNER))[t];
    zv.u = ((const uint4*)(z + (size_t)row * D_INNER))[t];
    float v[8];
    float ss = 0.f;
    #pragma unroll
    for (int i = 0; i < 8; i++){
        float a = b2f(yv.b[i]);
        float q = b2f(zv.b[i]);
        v[i] = a * silu_f(q);
        ss += v[i]*v[i];
    }
    ss = block_sum_256(ss);
    float sc = rsqrtf(ss * (1.0f/(float)D_INNER) + EPSF);
    const float4* g4 = (const float4*)g;
    float4 ga = g4[2*t], gb = g4[2*t+1];
    float gg[8] = {ga.x,ga.y,ga.z,ga.w,gb.x,gb.y,gb.z,gb.w};
    #pragma unroll
    for (int i = 0; i < 8; i++) ov.b[i] = f2b(v[i]*sc*gg[i]);
    ((uint4*)(yn + (size_t)row * D_INNER))[t] = ov.u;
}

// ---------------- GEMM2: yn[8192x2048]bf16 x W_out[1024x2048]^T + hidden ----------------
__global__ __launch_bounds__(256) void k_gemm2(const bf16* __restrict__ A,
                                               const float* __restrict__ B,
                                               const float* __restrict__ res,
                                               float* __restrict__ C){
    __shared__ float As[16][65];
    __shared__ float Bs[16][65];
    int bn = blockIdx.x * 64, bm = blockIdx.y * 64;
    int tid = threadIdx.x;
    int tr = tid >> 4, tc = tid & 15;
    float acc[4][4] = {};
    for (int k0 = 0; k0 < D_INNER; k0 += 16){
        #pragma unroll
        for (int i = 0; i < 4; i++){
            int idx = tid + i*256;
            int r = idx >> 4, c = idx & 15;
            As[c][r] = b2f(A[(size_t)(bm + r) * D_INNER + k0 + c]);
            Bs[c][r] = B[(size_t)(bn + r) * D_INNER + k0 + c];
        }
        __syncthreads();
        #pragma unroll
        for (int kk = 0; kk < 16; kk++){
            float a0 = As[kk][tr*4+0], a1 = As[kk][tr*4+1];
            float a2 = As[kk][tr*4+2], a3 = As[kk][tr*4+3];
            float b0 = Bs[kk][tc*4+0], b1 = Bs[kk][tc*4+1];
            float b2 = Bs[kk][tc*4+2], b3 = Bs[kk][tc*4+3];
            acc[0][0] += a0*b0; acc[0][1] += a0*b1; acc[0][2] += a0*b2; acc[0][3] += a0*b3;
            acc[1][0] += a1*b0; acc[1][1] += a1*b1; acc[1][2] += a1*b2; acc[1][3] += a1*b3;
            acc[2][0] += a2*b0; acc[2][1] += a2*b1; acc[2][2] += a2*b2; acc[2][3] += a2*b3;
            acc[3][0] += a3*b0; acc[3][1] += a3*b1; acc[3][2] += a3*b2; acc[3][3] += a3*b3;
        }
        __syncthreads();
    }
    #pragma unroll
    for (int i = 0; i < 4; i++){
        int r = bm + tr*4 + i;
        #pragma unroll
        for (int j = 0; j < 4; j++){
            int c = bn + tc*4 + j;
            C[(size_t)r * D_MODEL + c] = acc[i][j] + res[(size_t)r * D_MODEL + c];
        }
    }
}

extern "C" void kernel_launch(void* const* d_in, const int* in_sizes, int n_in,
                              void* d_out, int out_size, void* d_ws, size_t ws_size,
                              hipStream_t stream){
    const float* hidden = (const float*)d_in[0];
    const float* W_in   = (const float*)d_in[1];
    const float* conv_w = (const float*)d_in[2];
    const float* conv_b = (const float*)d_in[3];
    const float* W_dt   = (const float*)d_in[4];
    const float* b_dt   = (const float*)d_in[5];
    const float* A_log  = (const float*)d_in[6];
    const float* Dv     = (const float*)d_in[7];
    const float* W_out  = (const float*)d_in[8];
    const float* g_in   = (const float*)d_in[9];
    const float* g_out  = (const float*)d_in[10];

    // workspace layout (bytes) — total ~160.5 MiB
    char* ws = (char*)d_ws;
    bf16*  z    = (bf16*)(ws + 0);           //  33,554,432 B
    bf16*  xp   = (bf16*)(ws + 33554432);    //  33,554,432 B (later reused as yn)
    bf16*  x    = (bf16*)(ws + 67108864);    //  33,554,432 B (later y in place)
    bf16*  st   = (bf16*)(ws + 100663296);   //  33,554,432 B (scan in place -> h0)
    float* Bc   = (float*)(ws + 134217728);  //  16,777,216 B
    float* Cc   = (float*)(ws + 150994944);  //  16,777,216 B
    float* dtr  = (float*)(ws + 167772160);  //     262,144 B
    float* lcs  = (float*)(ws + 168034304);  //     262,144 B
    float* tdec = (float*)(ws + 168296448);  //       4,096 B
    float* misc = (float*)(ws + 168300544);  //         512 B
    bf16*  yn   = xp;                        // xp dead after conv
    float* hn   = (float*)d_out;             // d_out as scratch; overwritten by gemm2

    k_rms_in<<<ROWS, 256, 0, stream>>>(hidden, g_in, hn);
    k_gemm1<<<dim3((PROJ_N + 63)/64, ROWS/64), 256, 0, stream>>>(hn, W_in, z, xp, Bc, Cc, dtr);
    k_conv_silu<<<dim3(BATCH, D_INNER/256), 256, 0, stream>>>(xp, conv_w, conv_b, x);
    k_prep<<<1, 64, 0, stream>>>(W_dt, b_dt, A_log, misc);
    k_dt_lcs<<<BATCH*NCHUNK, 64, 0, stream>>>(dtr, misc, lcs, tdec);
    k_states<<<BATCH*NCHUNK*N_HEADS, 256, 0, stream>>>(Bc, x, lcs, st);
    k_scan<<<(BATCH*N_HEADS*HEAD_DIM*D_STATE)/256, 256, 0, stream>>>(st, tdec);
    k_intra_inter<<<BATCH*NCHUNK*N_HEADS, 256, 0, stream>>>(Bc, Cc, lcs, st, Dv, x);
    k_gate_rms<<<ROWS, 256, 0, stream>>>(x, z, g_out, yn);
    k_gemm2<<<dim3(D_MODEL/64, ROWS/64), 256, 0, stream>>>(yn, W_out, hidden, (float*)d_out);
}

// Round 3
// 607.743 us; speedup vs baseline: 4.6185x; 4.6185x over previous
//
#include <hip/hip_runtime.h>
#include <hip/hip_bf16.h>
#include <math.h>

typedef __hip_bfloat16 bf16;
typedef __attribute__((ext_vector_type(8))) short short8;
typedef __attribute__((ext_vector_type(4))) float f32x4;

#define AS1 __attribute__((address_space(1)))
#define AS3 __attribute__((address_space(3)))

#define D_MODEL 1024
#define D_INNER 2048
#define N_HEADS 8
#define D_STATE 64
#define CHUNK 64
#define HEAD_DIM 256
#define NCHUNK 4
#define BATCH 32
#define SEQ 256
#define ROWS (BATCH*SEQ)          // 8192
#define PROJ_N 5128
#define PROJ_NPAD 5248            // 41 tiles of 128
#define O1 D_INNER                // 2048
#define O2 (2*D_INNER)            // 4096
#define O3 (O2 + N_HEADS*D_STATE) // 4608
#define O4 (O3 + N_HEADS*D_STATE) // 5120
#define EPSF 1.1920929e-07f

__device__ __forceinline__ float silu_f(float x){ return x / (1.0f + expf(-x)); }
__device__ __forceinline__ float b2f(bf16 v){ return __bfloat162float(v); }
__device__ __forceinline__ bf16  f2b(float v){ return __float2bfloat16(v); }

__device__ __forceinline__ void gl16(const void* g, void* l){
    __builtin_amdgcn_global_load_lds((const AS1 void*)g, (AS3 void*)l, 16, 0, 0);
}

__device__ __forceinline__ float block_sum_256(float v){
    __shared__ float sm[4];
    #pragma unroll
    for (int o = 32; o > 0; o >>= 1) v += __shfl_down(v, o, 64);
    int lane = threadIdx.x & 63, w = threadIdx.x >> 6;
    if (lane == 0) sm[w] = v;
    __syncthreads();
    return sm[0] + sm[1] + sm[2] + sm[3];
}

// ---------------- RMSNorm (input) -> bf16 ----------------
__global__ __launch_bounds__(256) void k_rms_in(const float* __restrict__ x,
                                                const float* __restrict__ g,
                                                bf16* __restrict__ out){
    int row = blockIdx.x, t = threadIdx.x;
    const float4* xr = (const float4*)(x + (size_t)row * D_MODEL);
    float4 v = xr[t];
    float ss = v.x*v.x + v.y*v.y + v.z*v.z + v.w*v.w;
    ss = block_sum_256(ss);
    float sc = rsqrtf(ss * (1.0f/(float)D_MODEL) + EPSF);
    float4 gv = ((const float4*)g)[t];
    union { ushort4 u; bf16 b[4]; } o;
    o.b[0] = f2b(v.x*sc*gv.x); o.b[1] = f2b(v.y*sc*gv.y);
    o.b[2] = f2b(v.z*sc*gv.z); o.b[3] = f2b(v.w*sc*gv.w);
    ((ushort4*)(out + (size_t)row * D_MODEL))[t] = o.u;
}

// ---------------- f32 -> bf16 cast with zero-pad tail ----------------
__global__ __launch_bounds__(256) void k_cvt_pad(const float* __restrict__ in,
                                                 bf16* __restrict__ out,
                                                 int n_in, int n_out){
    int i = (blockIdx.x * 256 + threadIdx.x) * 4;
    if (i >= n_out) return;
    union { ushort4 u; bf16 b[4]; } o;
    if (i + 3 < n_in){
        float4 v = *(const float4*)(in + i);
        o.b[0]=f2b(v.x); o.b[1]=f2b(v.y); o.b[2]=f2b(v.z); o.b[3]=f2b(v.w);
    } else {
        #pragma unroll
        for (int j = 0; j < 4; j++) o.b[j] = f2b((i+j < n_in) ? in[i+j] : 0.f);
    }
    *(ushort4*)(out + i) = o.u;
}

// ---------------- MFMA GEMM mainloop: C_tile += A[bm:,:K] * B[bn:,:K]^T ----------------
// A: [M][K] bf16 row-major, B: [Npad][K] bf16 row-major. BM=BN=128, BK=32, 4 waves.
__device__ __forceinline__ void gemm_mainloop(const bf16* __restrict__ A,
                                              const bf16* __restrict__ B,
                                              int K, size_t bm, size_t bn,
                                              short* As, short* Bs,
                                              f32x4 acc[4][4]){
    const int tid = threadIdx.x;
    const int lane = tid & 63;
    const int wid = tid >> 6;            // 0..3
    const int wr = wid >> 1, wc = wid & 1;
    const int fr = lane & 15;
    const int fk = (lane >> 4) * 8;
    for (int k0 = 0; k0 < K; k0 += 32){
        #pragma unroll
        for (int i = 0; i < 2; i++){
            int slot = i*256 + wid*64 + lane;
            int row = slot >> 2, seg = slot & 3;
            size_t goff = (size_t)row * K + k0 + seg*8;
            int loff = (i*256 + wid*64) * 8;   // wave-uniform 16B-slot base (in shorts)
            gl16(A + (size_t)bm * K + goff, As + loff);
            gl16(B + (size_t)bn * K + goff, Bs + loff);
        }
        __syncthreads();
        short8 af[4], bfr[4];
        #pragma unroll
        for (int m = 0; m < 4; m++)
            af[m] = *(const short8*)(As + ((wr*64 + m*16 + fr) * 32 + fk));
        #pragma unroll
        for (int n = 0; n < 4; n++)
            bfr[n] = *(const short8*)(Bs + ((wc*64 + n*16 + fr) * 32 + fk));
        #pragma unroll
        for (int m = 0; m < 4; m++)
            #pragma unroll
            for (int n = 0; n < 4; n++)
                acc[m][n] = __builtin_amdgcn_mfma_f32_16x16x32_bf16(af[m], bfr[n], acc[m][n], 0, 0, 0);
        __syncthreads();
    }
}

// ---------------- GEMM1: hn[8192x1024] x W_in[5248x1024]^T, segmented epilogue ----------------
__global__ __launch_bounds__(256) void k_gemm1(const bf16* __restrict__ A,
                                               const bf16* __restrict__ B,
                                               bf16* __restrict__ z,
                                               bf16* __restrict__ xp,
                                               bf16* __restrict__ Bc,
                                               bf16* __restrict__ Cc,
                                               float* __restrict__ dtr){
    __shared__ short As[128*32];
    __shared__ short Bs[128*32];
    f32x4 acc[4][4] = {};
    size_t bm = (size_t)blockIdx.y * 128, bn = (size_t)blockIdx.x * 128;
    gemm_mainloop(A, B, D_MODEL, bm, bn, As, Bs, acc);
    const int lane = threadIdx.x & 63;
    const int wid = threadIdx.x >> 6;
    const int wr = wid >> 1, wc = wid & 1;
    int cr = (lane >> 4) * 4;
    int cc = lane & 15;
    #pragma unroll
    for (int m = 0; m < 4; m++){
        size_t r0 = bm + wr*64 + m*16 + cr;
        #pragma unroll
        for (int n = 0; n < 4; n++){
            int c = (int)bn + wc*64 + n*16 + cc;
            #pragma unroll
            for (int j = 0; j < 4; j++){
                float v = acc[m][n][j];
                size_t r = r0 + j;
                if (c < O1)            z  [r * D_INNER + c]        = f2b(v);
                else if (c < O2)       xp [r * D_INNER + (c - O1)] = f2b(v);
                else if (c < O3)       Bc [r * 512 + (c - O2)]     = f2b(v);
                else if (c < O4)       Cc [r * 512 + (c - O3)]     = f2b(v);
                else if (c < PROJ_N)   dtr[r * 8 + (c - O4)]       = v;
            }
        }
    }
}

// ---------------- GEMM2: yn[8192x2048] x W_out[1024x2048]^T + hidden -> f32 ----------------
__global__ __launch_bounds__(256) void k_gemm2(const bf16* __restrict__ A,
                                               const bf16* __restrict__ B,
                                               const float* __restrict__ res,
                                               float* __restrict__ C){
    __shared__ short As[128*32];
    __shared__ short Bs[128*32];
    f32x4 acc[4][4] = {};
    size_t bm = (size_t)blockIdx.y * 128, bn = (size_t)blockIdx.x * 128;
    gemm_mainloop(A, B, D_INNER, bm, bn, As, Bs, acc);
    const int lane = threadIdx.x & 63;
    const int wid = threadIdx.x >> 6;
    const int wr = wid >> 1, wc = wid & 1;
    int cr = (lane >> 4) * 4;
    int cc = lane & 15;
    #pragma unroll
    for (int m = 0; m < 4; m++){
        size_t r0 = bm + wr*64 + m*16 + cr;
        #pragma unroll
        for (int n = 0; n < 4; n++){
            size_t c = bn + wc*64 + n*16 + cc;
            #pragma unroll
            for (int j = 0; j < 4; j++){
                size_t r = r0 + j;
                C[r * D_MODEL + c] = acc[m][n][j] + res[r * D_MODEL + c];
            }
        }
    }
}

// ---------------- depthwise causal conv(4) + SiLU ----------------
__global__ __launch_bounds__(256) void k_conv_silu(const bf16* __restrict__ xp,
                                                   const float* __restrict__ cw,
                                                   const float* __restrict__ cb,
                                                   bf16* __restrict__ xout){
    int b = blockIdx.x;
    int c = blockIdx.y * 256 + threadIdx.x;
    float w0 = cw[c*4+0], w1 = cw[c*4+1], w2 = cw[c*4+2], w3 = cw[c*4+3];
    float bias = cb[c];
    const bf16* ib = xp + (size_t)b * SEQ * D_INNER + c;
    bf16* ob = xout + (size_t)b * SEQ * D_INNER + c;
    float x0 = 0.f, x1 = 0.f, x2 = 0.f;
    for (int s = 0; s < SEQ; s++){
        float x3 = b2f(ib[(size_t)s * D_INNER]);
        float a = x0*w0 + x1*w1 + x2*w2 + x3*w3 + bias;
        ob[(size_t)s * D_INNER] = f2b(silu_f(a));
        x0 = x1; x1 = x2; x2 = x3;
    }
}

// ---------------- precompute Wm (8x8), bm (8), A (8) ----------------
__global__ __launch_bounds__(64) void k_prep(const float* __restrict__ W_dt,
                                             const float* __restrict__ b_dt,
                                             const float* __restrict__ A_log,
                                             float* __restrict__ misc){
    int t = threadIdx.x;
    int h = t >> 3, k = t & 7;
    float s = 0.f;
    for (int d = 0; d < HEAD_DIM; d++) s += W_dt[(size_t)(h*HEAD_DIM + d) * N_HEADS + k];
    misc[t] = s * (1.0f/(float)HEAD_DIM);
    if (t < 8){
        float sb = 0.f;
        for (int d = 0; d < HEAD_DIM; d++) sb += b_dt[t*HEAD_DIM + d];
        misc[64 + t] = sb * (1.0f/(float)HEAD_DIM);
        misc[72 + t] = -expf(A_log[t]);
    }
}

// ---------------- dt_h -> logA cumsum (lcs) + tdec ----------------
__global__ __launch_bounds__(64) void k_dt_lcs(const float* __restrict__ dtr,
                                               const float* __restrict__ misc,
                                               float* __restrict__ lcs,
                                               float* __restrict__ tdec){
    __shared__ float sm[80];
    __shared__ float la[CHUNK][N_HEADS];
    int bc = blockIdx.x;
    int l = threadIdx.x;
    for (int i = l; i < 80; i += 64) sm[i] = misc[i];
    __syncthreads();
    const float* dr = dtr + (size_t)(bc*CHUNK + l) * 8;
    float d0 = dr[0], d1 = dr[1], d2 = dr[2], d3 = dr[3];
    float d4 = dr[4], d5 = dr[5], d6 = dr[6], d7 = dr[7];
    #pragma unroll
    for (int h = 0; h < 8; h++){
        float dt = sm[64+h]
                 + d0*sm[h*8+0] + d1*sm[h*8+1] + d2*sm[h*8+2] + d3*sm[h*8+3]
                 + d4*sm[h*8+4] + d5*sm[h*8+5] + d6*sm[h*8+6] + d7*sm[h*8+7];
        float sp = (dt > 20.f) ? dt : log1pf(expf(dt));
        la[l][h] = sp * sm[72+h];
    }
    __syncthreads();
    float out[8];
    #pragma unroll
    for (int h = 0; h < 8; h++) out[h] = 0.f;
    for (int l2 = 0; l2 <= l; l2++){
        #pragma unroll
        for (int h = 0; h < 8; h++) out[h] += la[l2][h];
    }
    float* lo = lcs + (size_t)(bc*CHUNK + l) * N_HEADS;
    #pragma unroll
    for (int h = 0; h < 8; h++) lo[h] = out[h];
    if (l == 63){
        #pragma unroll
        for (int h = 0; h < 8; h++) tdec[bc*N_HEADS + h] = expf(out[h]);
    }
}

// ---------------- states[d][n] = sum_s Mlast[s]*B[s,n]*x[s,d] ----------------
__global__ __launch_bounds__(256) void k_states(const bf16* __restrict__ Bc,
                                                const bf16* __restrict__ x,
                                                const float* __restrict__ lcs,
                                                bf16* __restrict__ states){
    int blk = blockIdx.x;       // (b*4+c)*8 + h
    int h = blk & 7, bc = blk >> 3;
    __shared__ float Bsm[CHUNK][D_STATE+1];
    __shared__ float ml[CHUNK];
    int tid = threadIdx.x;
    #pragma unroll
    for (int i = 0; i < 16; i++){
        int idx = tid + i*256;
        int s = idx >> 6, n = idx & 63;
        Bsm[s][n] = b2f(Bc[(size_t)(bc*CHUNK + s) * 512 + h*D_STATE + n]);
    }
    if (tid < 64){
        float l63 = lcs[(size_t)(bc*CHUNK + 63) * N_HEADS + h];
        ml[tid] = expf(l63 - lcs[(size_t)(bc*CHUNK + tid) * N_HEADS + h]);
    }
    __syncthreads();
    int d = tid;
    float xw[64];
    #pragma unroll
    for (int s = 0; s < 64; s++)
        xw[s] = b2f(x[(size_t)(bc*CHUNK + s) * D_INNER + h*HEAD_DIM + d]) * ml[s];
    bf16* so = states + (size_t)blk * (HEAD_DIM*D_STATE) + (size_t)d * D_STATE;
    for (int n = 0; n < 64; n++){
        float a = 0.f;
        #pragma unroll
        for (int s = 0; s < 64; s++) a += xw[s] * Bsm[s][n];
        so[n] = f2b(a);
    }
}

// ---------------- 4-chunk sequential scan, in place: states -> h0 ----------------
__global__ __launch_bounds__(256) void k_scan(bf16* __restrict__ states,
                                              const float* __restrict__ tdec){
    int idx = blockIdx.x * 256 + threadIdx.x;
    int dn = idx & 16383;
    int bh = idx >> 14;
    int b = bh >> 3, h = bh & 7;
    float carry = 0.f;
    #pragma unroll
    for (int c = 0; c < NCHUNK; c++){
        size_t s = ((size_t)((b*NCHUNK + c)*N_HEADS + h)) * 16384 + dn;
        float st = b2f(states[s]);
        states[s] = f2b(carry);
        carry = tdec[(b*NCHUNK + c)*N_HEADS + h] * carry + st;
    }
}

// ---------------- intra + inter + D-term -> y (in place over x) ----------------
__global__ __launch_bounds__(256) void k_intra_inter(const bf16* __restrict__ Bc,
                                                     const bf16* __restrict__ Cc,
                                                     const float* __restrict__ lcs,
                                                     const bf16* __restrict__ h0,
                                                     const float* __restrict__ Dv,
                                                     bf16* __restrict__ xy){
    int blk = blockIdx.x;       // (b*4+c)*8 + h
    int h = blk & 7, bc = blk >> 3;
    __shared__ float Cs[CHUNK][D_STATE+1];
    __shared__ float Bsm[CHUNK][D_STATE+1];
    __shared__ float GMT[CHUNK][CHUNK+1];   // GMT[s][l]
    __shared__ float el[CHUNK];
    int tid = threadIdx.x;
    #pragma unroll
    for (int i = 0; i < 16; i++){
        int idx = tid + i*256;
        int s = idx >> 6, n = idx & 63;
        size_t rb = (size_t)(bc*CHUNK + s) * 512 + h*D_STATE;
        Bsm[s][n] = b2f(Bc[rb + n]);
        Cs[s][n]  = b2f(Cc[rb + n]);
    }
    if (tid < 64) el[tid] = lcs[(size_t)(bc*CHUNK + tid) * N_HEADS + h];
    __syncthreads();
    #pragma unroll
    for (int i = 0; i < 16; i++){
        int idx = tid + i*256;
        int l = idx >> 6, s = idx & 63;
        float g = 0.f;
        if (s <= l){
            #pragma unroll
            for (int n = 0; n < 64; n++) g += Cs[l][n] * Bsm[s][n];
            g *= expf(el[l] - el[s]);
        }
        GMT[s][l] = g;
    }
    __syncthreads();
    int d = tid;
    float acc[64];
    #pragma unroll
    for (int l = 0; l < 64; l++) acc[l] = 0.f;
    const bf16* h0r = h0 + (size_t)blk * 16384 + (size_t)d * 64;
    for (int n = 0; n < 64; n++){
        float hn = b2f(h0r[n]);
        #pragma unroll
        for (int l = 0; l < 64; l++) acc[l] += Cs[l][n] * hn;
    }
    #pragma unroll
    for (int l = 0; l < 64; l++) acc[l] *= expf(el[l]);
    bf16* xb = xy + (size_t)(bc*CHUNK) * D_INNER + h*HEAD_DIM + d;
    for (int s = 0; s < 64; s++){
        float xv = b2f(xb[(size_t)s * D_INNER]);
        #pragma unroll
        for (int l = 0; l < 64; l++) acc[l] += GMT[s][l] * xv;
    }
    float Dh = Dv[h];
    #pragma unroll
    for (int l = 0; l < 64; l++){
        float xv = b2f(xb[(size_t)l * D_INNER]);
        xb[(size_t)l * D_INNER] = f2b(acc[l] + xv * Dh);
    }
}

// ---------------- gate with silu(z) + RMSNorm (output) -> yn bf16 ----------------
__global__ __launch_bounds__(256) void k_gate_rms(const bf16* __restrict__ y,
                                                  const bf16* __restrict__ z,
                                                  const float* __restrict__ g,
                                                  bf16* __restrict__ yn){
    int row = blockIdx.x, t = threadIdx.x;
    union { uint4 u; bf16 b[8]; } yv, zv, ov;
    yv.u = ((const uint4*)(y + (size_t)row * D_INNER))[t];
    zv.u = ((const uint4*)(z + (size_t)row * D_INNER))[t];
    float v[8];
    float ss = 0.f;
    #pragma unroll
    for (int i = 0; i < 8; i++){
        float a = b2f(yv.b[i]);
        float q = b2f(zv.b[i]);
        v[i] = a * silu_f(q);
        ss += v[i]*v[i];
    }
    ss = block_sum_256(ss);
    float sc = rsqrtf(ss * (1.0f/(float)D_INNER) + EPSF);
    const float4* g4 = (const float4*)g;
    float4 ga = g4[2*t], gb = g4[2*t+1];
    float gg[8] = {ga.x,ga.y,ga.z,ga.w,gb.x,gb.y,gb.z,gb.w};
    #pragma unroll
    for (int i = 0; i < 8; i++) ov.b[i] = f2b(v[i]*sc*gg[i]);
    ((uint4*)(yn + (size_t)row * D_INNER))[t] = ov.u;
}

extern "C" void kernel_launch(void* const* d_in, const int* in_sizes, int n_in,
                              void* d_out, int out_size, void* d_ws, size_t ws_size,
                              hipStream_t stream){
    const float* hidden = (const float*)d_in[0];
    const float* W_in   = (const float*)d_in[1];
    const float* conv_w = (const float*)d_in[2];
    const float* conv_b = (const float*)d_in[3];
    const float* W_dt   = (const float*)d_in[4];
    const float* b_dt   = (const float*)d_in[5];
    const float* A_log  = (const float*)d_in[6];
    const float* Dv     = (const float*)d_in[7];
    const float* W_out  = (const float*)d_in[8];
    const float* g_in   = (const float*)d_in[9];
    const float* g_out  = (const float*)d_in[10];

    // workspace layout (bytes) — total ~154.8 MiB
    char* ws = (char*)d_ws;
    bf16*  z    = (bf16*)(ws + 0);            // 33,554,432
    bf16*  xp   = (bf16*)(ws + 33554432);     // 33,554,432 (reused as yn)
    bf16*  x    = (bf16*)(ws + 67108864);     // 33,554,432 (y in place)
    bf16*  st   = (bf16*)(ws + 100663296);    // 33,554,432 (scan in place; first 16MB aliased by hnb)
    bf16*  Bc   = (bf16*)(ws + 134217728);    //  8,388,608
    bf16*  Cc   = (bf16*)(ws + 142606336);    //  8,388,608
    float* dtr  = (float*)(ws + 150994944);   //    262,144
    float* lcs  = (float*)(ws + 151257088);   //    262,144
    float* tdec = (float*)(ws + 151519232);   //      4,096
    float* misc = (float*)(ws + 151523328);   //        512
    bf16*  Wb   = (bf16*)(ws + 151523840);    // 10,747,904 (W_in_b; later W_out_b)
    bf16*  hnb  = st;                          // aliases st: dead before k_states writes
    bf16*  yn   = xp;                          // xp dead after conv

    k_rms_in<<<ROWS, 256, 0, stream>>>(hidden, g_in, hnb);
    k_cvt_pad<<<(PROJ_NPAD*D_MODEL/4 + 255)/256, 256, 0, stream>>>(W_in, Wb, PROJ_N*D_MODEL, PROJ_NPAD*D_MODEL);
    k_gemm1<<<dim3(PROJ_NPAD/128, ROWS/128), 256, 0, stream>>>(hnb, Wb, z, xp, Bc, Cc, dtr);
    k_conv_silu<<<dim3(BATCH, D_INNER/256), 256, 0, stream>>>(xp, conv_w, conv_b, x);
    k_prep<<<1, 64, 0, stream>>>(W_dt, b_dt, A_log, misc);
    k_dt_lcs<<<BATCH*NCHUNK, 64, 0, stream>>>(dtr, misc, lcs, tdec);
    k_states<<<BATCH*NCHUNK*N_HEADS, 256, 0, stream>>>(Bc, x, lcs, st);
    k_scan<<<(BATCH*N_HEADS*HEAD_DIM*D_STATE)/256, 256, 0, stream>>>(st, tdec);
    k_intra_inter<<<BATCH*NCHUNK*N_HEADS, 256, 0, stream>>>(Bc, Cc, lcs, st, Dv, x);
    k_gate_rms<<<ROWS, 256, 0, stream>>>(x, z, g_out, yn);
    k_cvt_pad<<<(D_MODEL*D_INNER/4 + 255)/256, 256, 0, stream>>>(W_out, Wb, D_MODEL*D_INNER, D_MODEL*D_INNER);
    k_gemm2<<<dim3(D_MODEL/128, ROWS/128), 256, 0, stream>>>(yn, Wb, hidden, (float*)d_out);
}

// Round 4
// 364.333 us; speedup vs baseline: 7.7042x; 1.6681x over previous
//
#include <hip/hip_runtime.h>
#include <hip/hip_bf16.h>
#include <math.h>

typedef __hip_bfloat16 bf16;
typedef __attribute__((ext_vector_type(8))) short short8;
typedef __attribute__((ext_vector_type(4))) float f32x4;

#define AS1 __attribute__((address_space(1)))
#define AS3 __attribute__((address_space(3)))

#define D_MODEL 1024
#define D_INNER 2048
#define N_HEADS 8
#define D_STATE 64
#define CHUNK 64
#define HEAD_DIM 256
#define NCHUNK 4
#define BATCH 32
#define SEQ 256
#define ROWS (BATCH*SEQ)          // 8192
#define PROJ_N 5128
#define PROJ_NPAD 5248            // 41 tiles of 128
#define O1 D_INNER                // 2048
#define O2 (2*D_INNER)            // 4096
#define O3 (O2 + N_HEADS*D_STATE) // 4608
#define O4 (O3 + N_HEADS*D_STATE) // 5120
#define EPSF 1.1920929e-07f

__device__ __forceinline__ float silu_f(float x){ return x / (1.0f + expf(-x)); }
__device__ __forceinline__ float b2f(bf16 v){ return __bfloat162float(v); }
__device__ __forceinline__ bf16  f2b(float v){ return __float2bfloat16(v); }
__device__ __forceinline__ short f2s(float v){ bf16 b = __float2bfloat16(v); union{bf16 b; short s;} u; u.b=b; return u.s; }
__device__ __forceinline__ float s2f(short v){ union{short s; bf16 b;} u; u.s=v; return __bfloat162float(u.b); }

__device__ __forceinline__ void gl16(const void* g, void* l){
    __builtin_amdgcn_global_load_lds((const AS1 void*)g, (AS3 void*)l, 16, 0, 0);
}

__device__ __forceinline__ float block_sum_256(float v){
    __shared__ float sm[4];
    #pragma unroll
    for (int o = 32; o > 0; o >>= 1) v += __shfl_down(v, o, 64);
    int lane = threadIdx.x & 63, w = threadIdx.x >> 6;
    if (lane == 0) sm[w] = v;
    __syncthreads();
    return sm[0] + sm[1] + sm[2] + sm[3];
}

// ---------------- RMSNorm (input) -> bf16 ----------------
__global__ __launch_bounds__(256) void k_rms_in(const float* __restrict__ x,
                                                const float* __restrict__ g,
                                                bf16* __restrict__ out){
    int row = blockIdx.x, t = threadIdx.x;
    const float4* xr = (const float4*)(x + (size_t)row * D_MODEL);
    float4 v = xr[t];
    float ss = v.x*v.x + v.y*v.y + v.z*v.z + v.w*v.w;
    ss = block_sum_256(ss);
    float sc = rsqrtf(ss * (1.0f/(float)D_MODEL) + EPSF);
    float4 gv = ((const float4*)g)[t];
    union { ushort4 u; bf16 b[4]; } o;
    o.b[0] = f2b(v.x*sc*gv.x); o.b[1] = f2b(v.y*sc*gv.y);
    o.b[2] = f2b(v.z*sc*gv.z); o.b[3] = f2b(v.w*sc*gv.w);
    ((ushort4*)(out + (size_t)row * D_MODEL))[t] = o.u;
}

// ---------------- f32 -> bf16 cast with zero-pad tail ----------------
__global__ __launch_bounds__(256) void k_cvt_pad(const float* __restrict__ in,
                                                 bf16* __restrict__ out,
                                                 int n_in, int n_out){
    int i = (blockIdx.x * 256 + threadIdx.x) * 4;
    if (i >= n_out) return;
    union { ushort4 u; bf16 b[4]; } o;
    if (i + 3 < n_in){
        float4 v = *(const float4*)(in + i);
        o.b[0]=f2b(v.x); o.b[1]=f2b(v.y); o.b[2]=f2b(v.z); o.b[3]=f2b(v.w);
    } else {
        #pragma unroll
        for (int j = 0; j < 4; j++) o.b[j] = f2b((i+j < n_in) ? in[i+j] : 0.f);
    }
    *(ushort4*)(out + i) = o.u;
}

// ---------------- MFMA GEMM mainloop (m97 structure) ----------------
__device__ __forceinline__ void gemm_mainloop(const bf16* __restrict__ A,
                                              const bf16* __restrict__ B,
                                              int K, size_t bm, size_t bn,
                                              short* As, short* Bs,
                                              f32x4 acc[4][4]){
    const int tid = threadIdx.x;
    const int lane = tid & 63;
    const int wid = tid >> 6;
    const int wr = wid >> 1, wc = wid & 1;
    const int fr = lane & 15;
    const int fk = (lane >> 4) * 8;
    for (int k0 = 0; k0 < K; k0 += 32){
        #pragma unroll
        for (int i = 0; i < 2; i++){
            int slot = i*256 + wid*64 + lane;
            int row = slot >> 2, seg = slot & 3;
            size_t goff = (size_t)row * K + k0 + seg*8;
            int loff = (i*256 + wid*64) * 8;
            gl16(A + (size_t)bm * K + goff, As + loff);
            gl16(B + (size_t)bn * K + goff, Bs + loff);
        }
        __syncthreads();
        short8 af[4], bfr[4];
        #pragma unroll
        for (int m = 0; m < 4; m++)
            af[m] = *(const short8*)(As + ((wr*64 + m*16 + fr) * 32 + fk));
        #pragma unroll
        for (int n = 0; n < 4; n++)
            bfr[n] = *(const short8*)(Bs + ((wc*64 + n*16 + fr) * 32 + fk));
        #pragma unroll
        for (int m = 0; m < 4; m++)
            #pragma unroll
            for (int n = 0; n < 4; n++)
                acc[m][n] = __builtin_amdgcn_mfma_f32_16x16x32_bf16(af[m], bfr[n], acc[m][n], 0, 0, 0);
        __syncthreads();
    }
}

// ---------------- GEMM1: segmented epilogue ----------------
__global__ __launch_bounds__(256) void k_gemm1(const bf16* __restrict__ A,
                                               const bf16* __restrict__ B,
                                               bf16* __restrict__ z,
                                               bf16* __restrict__ xp,
                                               bf16* __restrict__ Bc,
                                               bf16* __restrict__ Cc,
                                               float* __restrict__ dtr){
    __shared__ short As[128*32];
    __shared__ short Bs[128*32];
    f32x4 acc[4][4] = {};
    size_t bm = (size_t)blockIdx.y * 128, bn = (size_t)blockIdx.x * 128;
    gemm_mainloop(A, B, D_MODEL, bm, bn, As, Bs, acc);
    const int lane = threadIdx.x & 63;
    const int wid = threadIdx.x >> 6;
    const int wr = wid >> 1, wc = wid & 1;
    int cr = (lane >> 4) * 4;
    int cc = lane & 15;
    #pragma unroll
    for (int m = 0; m < 4; m++){
        size_t r0 = bm + wr*64 + m*16 + cr;
        #pragma unroll
        for (int n = 0; n < 4; n++){
            int c = (int)bn + wc*64 + n*16 + cc;
            #pragma unroll
            for (int j = 0; j < 4; j++){
                float v = acc[m][n][j];
                size_t r = r0 + j;
                if (c < O1)            z  [r * D_INNER + c]        = f2b(v);
                else if (c < O2)       xp [r * D_INNER + (c - O1)] = f2b(v);
                else if (c < O3)       Bc [r * 512 + (c - O2)]     = f2b(v);
                else if (c < O4)       Cc [r * 512 + (c - O3)]     = f2b(v);
                else if (c < PROJ_N)   dtr[r * 8 + (c - O4)]       = v;
            }
        }
    }
}

// ---------------- GEMM2: + residual -> f32 ----------------
__global__ __launch_bounds__(256) void k_gemm2(const bf16* __restrict__ A,
                                               const bf16* __restrict__ B,
                                               const float* __restrict__ res,
                                               float* __restrict__ C){
    __shared__ short As[128*32];
    __shared__ short Bs[128*32];
    f32x4 acc[4][4] = {};
    size_t bm = (size_t)blockIdx.y * 128, bn = (size_t)blockIdx.x * 128;
    gemm_mainloop(A, B, D_INNER, bm, bn, As, Bs, acc);
    const int lane = threadIdx.x & 63;
    const int wid = threadIdx.x >> 6;
    const int wr = wid >> 1, wc = wid & 1;
    int cr = (lane >> 4) * 4;
    int cc = lane & 15;
    #pragma unroll
    for (int m = 0; m < 4; m++){
        size_t r0 = bm + wr*64 + m*16 + cr;
        #pragma unroll
        for (int n = 0; n < 4; n++){
            size_t c = bn + wc*64 + n*16 + cc;
            #pragma unroll
            for (int j = 0; j < 4; j++){
                size_t r = r0 + j;
                C[r * D_MODEL + c] = acc[m][n][j] + res[r * D_MODEL + c];
            }
        }
    }
}

// ---------------- depthwise causal conv(4) + SiLU ----------------
__global__ __launch_bounds__(256) void k_conv_silu(const bf16* __restrict__ xp,
                                                   const float* __restrict__ cw,
                                                   const float* __restrict__ cb,
                                                   bf16* __restrict__ xout){
    int b = blockIdx.x;
    int c = blockIdx.y * 256 + threadIdx.x;
    float w0 = cw[c*4+0], w1 = cw[c*4+1], w2 = cw[c*4+2], w3 = cw[c*4+3];
    float bias = cb[c];
    const bf16* ib = xp + (size_t)b * SEQ * D_INNER + c;
    bf16* ob = xout + (size_t)b * SEQ * D_INNER + c;
    float x0 = 0.f, x1 = 0.f, x2 = 0.f;
    for (int s = 0; s < SEQ; s++){
        float x3 = b2f(ib[(size_t)s * D_INNER]);
        float a = x0*w0 + x1*w1 + x2*w2 + x3*w3 + bias;
        ob[(size_t)s * D_INNER] = f2b(silu_f(a));
        x0 = x1; x1 = x2; x2 = x3;
    }
}

// ---------------- precompute Wm (8x8), bm (8), A (8) ----------------
__global__ __launch_bounds__(64) void k_prep(const float* __restrict__ W_dt,
                                             const float* __restrict__ b_dt,
                                             const float* __restrict__ A_log,
                                             float* __restrict__ misc){
    int t = threadIdx.x;
    int h = t >> 3, k = t & 7;
    float s = 0.f;
    for (int d = 0; d < HEAD_DIM; d++) s += W_dt[(size_t)(h*HEAD_DIM + d) * N_HEADS + k];
    misc[t] = s * (1.0f/(float)HEAD_DIM);
    if (t < 8){
        float sb = 0.f;
        for (int d = 0; d < HEAD_DIM; d++) sb += b_dt[t*HEAD_DIM + d];
        misc[64 + t] = sb * (1.0f/(float)HEAD_DIM);
        misc[72 + t] = -expf(A_log[t]);
    }
}

// ---------------- dt_h -> logA cumsum (lcs) + tdec ----------------
__global__ __launch_bounds__(64) void k_dt_lcs(const float* __restrict__ dtr,
                                               const float* __restrict__ misc,
                                               float* __restrict__ lcs,
                                               float* __restrict__ tdec){
    __shared__ float sm[80];
    __shared__ float la[CHUNK][N_HEADS];
    int bc = blockIdx.x;
    int l = threadIdx.x;
    for (int i = l; i < 80; i += 64) sm[i] = misc[i];
    __syncthreads();
    const float* dr = dtr + (size_t)(bc*CHUNK + l) * 8;
    float d0 = dr[0], d1 = dr[1], d2 = dr[2], d3 = dr[3];
    float d4 = dr[4], d5 = dr[5], d6 = dr[6], d7 = dr[7];
    #pragma unroll
    for (int h = 0; h < 8; h++){
        float dt = sm[64+h]
                 + d0*sm[h*8+0] + d1*sm[h*8+1] + d2*sm[h*8+2] + d3*sm[h*8+3]
                 + d4*sm[h*8+4] + d5*sm[h*8+5] + d6*sm[h*8+6] + d7*sm[h*8+7];
        float sp = (dt > 20.f) ? dt : log1pf(expf(dt));
        la[l][h] = sp * sm[72+h];
    }
    __syncthreads();
    float out[8];
    #pragma unroll
    for (int h = 0; h < 8; h++) out[h] = 0.f;
    for (int l2 = 0; l2 <= l; l2++){
        #pragma unroll
        for (int h = 0; h < 8; h++) out[h] += la[l2][h];
    }
    float* lo = lcs + (size_t)(bc*CHUNK + l) * N_HEADS;
    #pragma unroll
    for (int h = 0; h < 8; h++) lo[h] = out[h];
    if (l == 63){
        #pragma unroll
        for (int h = 0; h < 8; h++) tdec[bc*N_HEADS + h] = expf(out[h]);
    }
}

// ================= fused chunked SSM: states+scan+intra+inter, all MFMA =================
// One block per (b,h); 4 waves; loops c=0..3 with carry in registers.
// LDS layout (shorts):
#define LB   0        // B [64][64] swizzled  (later Bt = B^T * ml)
#define LC   4096     // C [64][64] swizzled  (scaled in place to C*exp(el) after G)
#define LGM  8192     // GM [64][72] bf16
#define LXT  12800    // xT [256][64] swizzled
#define LSH  29184    // shared: x_rm [64][256] linear  ->  h0lds [256][64] swizzled
#define LF   45568    // floats: el[64], ml[64], ee[64]
#define LDS_BYTES 91904

__device__ __forceinline__ short8 frag_sw(const short* arr, int r, int k){
    return *(const short8*)(arr + r*64 + (k ^ ((r&7)<<3)));
}

__global__ __launch_bounds__(256, 1) void k_ssm(const bf16* __restrict__ Bc,
                                                const bf16* __restrict__ Cc,
                                                bf16* xg,
                                                const float* __restrict__ lcs,
                                                const float* __restrict__ tdec,
                                                const float* __restrict__ Dv){
    extern __shared__ short lds[];
    short* Blds  = lds + LB;
    short* Clds  = lds + LC;
    short* GMlds = lds + LGM;
    short* XTlds = lds + LXT;
    short* Shr   = lds + LSH;
    float* el = (float*)(lds + LF);
    float* ml = el + 64;
    float* ee = el + 128;

    const int tid = threadIdx.x;
    const int lane = tid & 63;
    const int wid = tid >> 6;
    const int fr = lane & 15;
    const int fk = (lane >> 4) * 8;
    const int r0 = (lane >> 4) * 4;
    const int b = blockIdx.x >> 3, h = blockIdx.x & 7;
    const float Dh = Dv[h];

    f32x4 carry[4][4] = {};

    for (int c = 0; c < NCHUNK; c++){
        const int bc = b*NCHUNK + c;
        __syncthreads();   // S0: previous chunk fully consumed
        // ---- stage B, C (pre-swizzled global source, linear LDS dest) ----
        #pragma unroll
        for (int i = 0; i < 2; i++){
            int slot = i*256 + tid;
            int s = slot >> 3, u = slot & 7;
            size_t rb = (size_t)(bc*CHUNK + s) * 512 + h*64 + ((u ^ (s&7)) * 8);
            gl16(Bc + rb, Blds + slot*8);
            gl16(Cc + rb, Clds + slot*8);
        }
        // ---- stage x_rm [64][256] linear ----
        #pragma unroll
        for (int i = 0; i < 8; i++){
            int slot = i*256 + tid;
            int s = slot >> 5, ck = slot & 31;
            gl16(xg + (size_t)(bc*CHUNK + s) * D_INNER + h*HEAD_DIM + ck*8, Shr + slot*8);
        }
        if (tid < 64) el[tid] = lcs[(size_t)(bc*CHUNK + tid) * N_HEADS + h];
        __syncthreads();   // S1: staging + el done
        // ---- P1: ml/ee; build xT from x_rm ----
        if (tid < 64){
            float e63 = el[63];
            ml[tid] = expf(e63 - el[tid]);
            ee[tid] = expf(el[tid]);
        }
        #pragma unroll
        for (int i = 0; i < 8; i++){
            short8 t8;
            #pragma unroll
            for (int j = 0; j < 8; j++) t8[j] = Shr[(i*8 + j)*HEAD_DIM + tid];
            *(short8*)(XTlds + tid*64 + ((i*8) ^ ((tid&7)<<3))) = t8;
        }
        __syncthreads();   // S2: xT ready, ml/ee ready, x_rm dead
        // ---- P2: G mfma; mask->GM; scale own C rows; h0lds write; Bt reg-read ----
        {
            f32x4 accg[4] = {};
            #pragma unroll
            for (int kk = 0; kk < 2; kk++){
                short8 a = frag_sw(Clds, wid*16 + fr, kk*32 + fk);
                #pragma unroll
                for (int nt = 0; nt < 4; nt++){
                    short8 bb = frag_sw(Blds, nt*16 + fr, kk*32 + fk);
                    accg[nt] = __builtin_amdgcn_mfma_f32_16x16x32_bf16(a, bb, accg[nt], 0, 0, 0);
                }
            }
            #pragma unroll
            for (int nt = 0; nt < 4; nt++){
                int s = nt*16 + fr;
                float els = el[s];
                #pragma unroll
                for (int j = 0; j < 4; j++){
                    int l = wid*16 + r0 + j;
                    float f = (s <= l) ? expf(el[l] - els) : 0.f;
                    GMlds[l*72 + s] = f2s(accg[nt][j] * f);
                }
            }
            // scale this wave's C rows (l = wid*16..+15) by ee[l]: Ce in place
            int crow = wid*16 + (lane >> 2), cq = lane & 3;
            float fe = ee[crow];
            #pragma unroll
            for (int half = 0; half < 2; half++){
                short8 v = *(short8*)(Clds + crow*64 + cq*16 + half*8);
                #pragma unroll
                for (int j = 0; j < 8; j++) v[j] = f2s(s2f(v[j]) * fe);
                *(short8*)(Clds + crow*64 + cq*16 + half*8) = v;
            }
        }
        // h0lds (over x_rm space) from carry
        #pragma unroll
        for (int mt = 0; mt < 4; mt++)
            #pragma unroll
            for (int nt = 0; nt < 4; nt++)
                #pragma unroll
                for (int j = 0; j < 4; j++){
                    int d = wid*64 + mt*16 + r0 + j;
                    int n = nt*16 + fr;
                    Shr[d*64 + (n ^ ((d&7)<<3))] = f2s(carry[mt][nt][j]);
                }
        // Bt values into regs (B^T with ml fold)
        float btv[16];
        {
            int bn_ = tid & 63, bq = tid >> 6;
            #pragma unroll
            for (int i = 0; i < 16; i++){
                int s = bq*16 + i;
                btv[i] = s2f(Blds[s*64 + (bn_ ^ ((s&7)<<3))]) * ml[s];
            }
        }
        __syncthreads();   // S3: G/Bt reads of B done; GM, Ce, h0lds ready
        // ---- P3: write Bt; intra+inter mfma; y epilogue ----
        {
            int bn_ = tid & 63, bq = tid >> 6;
            #pragma unroll
            for (int i = 0; i < 16; i++){
                int s = bq*16 + i;
                Blds[bn_*64 + (s ^ ((bn_&7)<<3))] = f2s(btv[i]);
            }
        }
        {
            f32x4 accy[4][4] = {};
            #pragma unroll
            for (int kk = 0; kk < 2; kk++){
                short8 ag[4], ae[4], bx[4], bh[4];
                #pragma unroll
                for (int mt = 0; mt < 4; mt++){
                    ag[mt] = *(const short8*)(GMlds + (mt*16 + fr)*72 + kk*32 + fk);
                    ae[mt] = frag_sw(Clds, mt*16 + fr, kk*32 + fk);
                }
                #pragma unroll
                for (int nt = 0; nt < 4; nt++){
                    int d = wid*64 + nt*16 + fr;
                    bx[nt] = frag_sw(XTlds, d, kk*32 + fk);
                    bh[nt] = frag_sw(Shr,  d, kk*32 + fk);
                }
                #pragma unroll
                for (int mt = 0; mt < 4; mt++)
                    #pragma unroll
                    for (int nt = 0; nt < 4; nt++){
                        accy[mt][nt] = __builtin_amdgcn_mfma_f32_16x16x32_bf16(ag[mt], bx[nt], accy[mt][nt], 0, 0, 0);
                        accy[mt][nt] = __builtin_amdgcn_mfma_f32_16x16x32_bf16(ae[mt], bh[nt], accy[mt][nt], 0, 0, 0);
                    }
            }
            // epilogue: y = accy + x*Dh, in place into xg
            #pragma unroll
            for (int mt = 0; mt < 4; mt++)
                #pragma unroll
                for (int nt = 0; nt < 4; nt++){
                    int d = wid*64 + nt*16 + fr;
                    #pragma unroll
                    for (int j = 0; j < 4; j++){
                        int l = mt*16 + r0 + j;
                        float xv = s2f(XTlds[d*64 + (l ^ ((d&7)<<3))]);
                        xg[(size_t)(bc*CHUNK + l) * D_INNER + h*HEAD_DIM + d] = f2b(accy[mt][nt][j] + xv*Dh);
                    }
                }
        }
        __syncthreads();   // S4: Bt written; epilogue xT reads done
        // ---- P4: states mfma; carry update ----
        {
            f32x4 accs[4][4] = {};
            #pragma unroll
            for (int kk = 0; kk < 2; kk++){
                short8 ax[4], bt[4];
                #pragma unroll
                for (int mt = 0; mt < 4; mt++)
                    ax[mt] = frag_sw(XTlds, wid*64 + mt*16 + fr, kk*32 + fk);
                #pragma unroll
                for (int nt = 0; nt < 4; nt++)
                    bt[nt] = frag_sw(Blds, nt*16 + fr, kk*32 + fk);
                #pragma unroll
                for (int mt = 0; mt < 4; mt++)
                    #pragma unroll
                    for (int nt = 0; nt < 4; nt++)
                        accs[mt][nt] = __builtin_amdgcn_mfma_f32_16x16x32_bf16(ax[mt], bt[nt], accs[mt][nt], 0, 0, 0);
            }
            float td = tdec[bc*N_HEADS + h];
            #pragma unroll
            for (int mt = 0; mt < 4; mt++)
                #pragma unroll
                for (int nt = 0; nt < 4; nt++)
                    carry[mt][nt] = td * carry[mt][nt] + accs[mt][nt];
        }
    }
}

// ---------------- gate with silu(z) + RMSNorm (output) -> yn bf16 ----------------
__global__ __launch_bounds__(256) void k_gate_rms(const bf16* __restrict__ y,
                                                  const bf16* __restrict__ z,
                                                  const float* __restrict__ g,
                                                  bf16* __restrict__ yn){
    int row = blockIdx.x, t = threadIdx.x;
    union { uint4 u; bf16 b[8]; } yv, zv, ov;
    yv.u = ((const uint4*)(y + (size_t)row * D_INNER))[t];
    zv.u = ((const uint4*)(z + (size_t)row * D_INNER))[t];
    float v[8];
    float ss = 0.f;
    #pragma unroll
    for (int i = 0; i < 8; i++){
        float a = b2f(yv.b[i]);
        float q = b2f(zv.b[i]);
        v[i] = a * silu_f(q);
        ss += v[i]*v[i];
    }
    ss = block_sum_256(ss);
    float sc = rsqrtf(ss * (1.0f/(float)D_INNER) + EPSF);
    const float4* g4 = (const float4*)g;
    float4 ga = g4[2*t], gb = g4[2*t+1];
    float gg[8] = {ga.x,ga.y,ga.z,ga.w,gb.x,gb.y,gb.z,gb.w};
    #pragma unroll
    for (int i = 0; i < 8; i++) ov.b[i] = f2b(v[i]*sc*gg[i]);
    ((uint4*)(yn + (size_t)row * D_INNER))[t] = ov.u;
}

extern "C" void kernel_launch(void* const* d_in, const int* in_sizes, int n_in,
                              void* d_out, int out_size, void* d_ws, size_t ws_size,
                              hipStream_t stream){
    const float* hidden = (const float*)d_in[0];
    const float* W_in   = (const float*)d_in[1];
    const float* conv_w = (const float*)d_in[2];
    const float* conv_b = (const float*)d_in[3];
    const float* W_dt   = (const float*)d_in[4];
    const float* b_dt   = (const float*)d_in[5];
    const float* A_log  = (const float*)d_in[6];
    const float* Dv     = (const float*)d_in[7];
    const float* W_out  = (const float*)d_in[8];
    const float* g_in   = (const float*)d_in[9];
    const float* g_out  = (const float*)d_in[10];

    // workspace layout (bytes) — total ~138.8 MiB
    char* ws = (char*)d_ws;
    bf16*  z    = (bf16*)(ws + 0);            // 33,554,432
    bf16*  xp   = (bf16*)(ws + 33554432);     // 33,554,432 (reused as yn)
    bf16*  x    = (bf16*)(ws + 67108864);     // 33,554,432 (y in place via k_ssm)
    bf16*  Bc   = (bf16*)(ws + 100663296);    //  8,388,608
    bf16*  Cc   = (bf16*)(ws + 109051904);    //  8,388,608
    float* dtr  = (float*)(ws + 117440512);   //    262,144
    float* lcs  = (float*)(ws + 117702656);   //    262,144
    float* tdec = (float*)(ws + 117964800);   //      4,096
    float* misc = (float*)(ws + 117968896);   //        512
    bf16*  Wb   = (bf16*)(ws + 117969408);    // 10,747,904 (W_in_b; later W_out_b)
    bf16*  hnb  = (bf16*)(ws + 128717312);    // 16,777,216
    bf16*  yn   = xp;                          // xp dead after conv

    k_rms_in<<<ROWS, 256, 0, stream>>>(hidden, g_in, hnb);
    k_cvt_pad<<<(PROJ_NPAD*D_MODEL/4 + 255)/256, 256, 0, stream>>>(W_in, Wb, PROJ_N*D_MODEL, PROJ_NPAD*D_MODEL);
    k_gemm1<<<dim3(PROJ_NPAD/128, ROWS/128), 256, 0, stream>>>(hnb, Wb, z, xp, Bc, Cc, dtr);
    k_conv_silu<<<dim3(BATCH, D_INNER/256), 256, 0, stream>>>(xp, conv_w, conv_b, x);
    k_prep<<<1, 64, 0, stream>>>(W_dt, b_dt, A_log, misc);
    k_dt_lcs<<<BATCH*NCHUNK, 64, 0, stream>>>(dtr, misc, lcs, tdec);
    hipFuncSetAttribute((const void*)k_ssm, hipFuncAttributeMaxDynamicSharedMemorySize, LDS_BYTES);
    k_ssm<<<BATCH*N_HEADS, 256, LDS_BYTES, stream>>>(Bc, Cc, x, lcs, tdec, Dv);
    k_gate_rms<<<ROWS, 256, 0, stream>>>(x, z, g_out, yn);
    k_cvt_pad<<<(D_MODEL*D_INNER/4 + 255)/256, 256, 0, stream>>>(W_out, Wb, D_MODEL*D_INNER, D_MODEL*D_INNER);
    k_gemm2<<<dim3(D_MODEL/128, ROWS/128), 256, 0, stream>>>(yn, Wb, hidden, (float*)d_out);
}

// Round 5
// 352.109 us; speedup vs baseline: 7.9716x; 1.0347x over previous
//
#include <hip/hip_runtime.h>
#include <hip/hip_bf16.h>
#include <math.h>

typedef __hip_bfloat16 bf16;
typedef __attribute__((ext_vector_type(8))) short short8;
typedef __attribute__((ext_vector_type(4))) float f32x4;

#define AS1 __attribute__((address_space(1)))
#define AS3 __attribute__((address_space(3)))

#define D_MODEL 1024
#define D_INNER 2048
#define N_HEADS 8
#define D_STATE 64
#define CHUNK 64
#define HEAD_DIM 256
#define NCHUNK 4
#define BATCH 32
#define SEQ 256
#define ROWS (BATCH*SEQ)          // 8192
#define PROJ_N 5128
#define PROJ_NPAD 5376            // 21 tiles of 256
#define O1 D_INNER                // 2048
#define O2 (2*D_INNER)            // 4096
#define O3 (O2 + N_HEADS*D_STATE) // 4608
#define O4 (O3 + N_HEADS*D_STATE) // 5120
#define EPSF 1.1920929e-07f

__device__ __forceinline__ float silu_f(float x){ return x / (1.0f + expf(-x)); }
__device__ __forceinline__ float b2f(bf16 v){ return __bfloat162float(v); }
__device__ __forceinline__ bf16  f2b(float v){ return __float2bfloat16(v); }
__device__ __forceinline__ short f2s(float v){ bf16 b = __float2bfloat16(v); union{bf16 b; short s;} u; u.b=b; return u.s; }
__device__ __forceinline__ float s2f(short v){ union{short s; bf16 b;} u; u.s=v; return __bfloat162float(u.b); }

__device__ __forceinline__ void gl16(const void* g, void* l){
    __builtin_amdgcn_global_load_lds((const AS1 void*)g, (AS3 void*)l, 16, 0, 0);
}

__device__ __forceinline__ float block_sum_256(float v){
    __shared__ float sm[4];
    #pragma unroll
    for (int o = 32; o > 0; o >>= 1) v += __shfl_down(v, o, 64);
    int lane = threadIdx.x & 63, w = threadIdx.x >> 6;
    if (lane == 0) sm[w] = v;
    __syncthreads();
    return sm[0] + sm[1] + sm[2] + sm[3];
}

// ---------------- RMSNorm (input) -> bf16 ----------------
__global__ __launch_bounds__(256) void k_rms_in(const float* __restrict__ x,
                                                const float* __restrict__ g,
                                                bf16* __restrict__ out){
    int row = blockIdx.x, t = threadIdx.x;
    const float4* xr = (const float4*)(x + (size_t)row * D_MODEL);
    float4 v = xr[t];
    float ss = v.x*v.x + v.y*v.y + v.z*v.z + v.w*v.w;
    ss = block_sum_256(ss);
    float sc = rsqrtf(ss * (1.0f/(float)D_MODEL) + EPSF);
    float4 gv = ((const float4*)g)[t];
    union { ushort4 u; bf16 b[4]; } o;
    o.b[0] = f2b(v.x*sc*gv.x); o.b[1] = f2b(v.y*sc*gv.y);
    o.b[2] = f2b(v.z*sc*gv.z); o.b[3] = f2b(v.w*sc*gv.w);
    ((ushort4*)(out + (size_t)row * D_MODEL))[t] = o.u;
}

// ---------------- f32 -> bf16 cast with zero-pad tail ----------------
__global__ __launch_bounds__(256) void k_cvt_pad(const float* __restrict__ in,
                                                 bf16* __restrict__ out,
                                                 int n_in, int n_out){
    int i = (blockIdx.x * 256 + threadIdx.x) * 4;
    if (i >= n_out) return;
    union { ushort4 u; bf16 b[4]; } o;
    if (i + 3 < n_in){
        float4 v = *(const float4*)(in + i);
        o.b[0]=f2b(v.x); o.b[1]=f2b(v.y); o.b[2]=f2b(v.z); o.b[3]=f2b(v.w);
    } else {
        #pragma unroll
        for (int j = 0; j < 4; j++) o.b[j] = f2b((i+j < n_in) ? in[i+j] : 0.f);
    }
    *(ushort4*)(out + i) = o.u;
}

// ================= deep-pipelined NT GEMM template =================
// A [M][K], B [N][K] bf16 K-major. BM = MT*32 (MT mfrags/wave), BN = 256.
// 512 threads = 8 waves (2 wave-rows x 4 wave-cols). Per-wave out: MT*16 x 64.
// LDS: double-buffered [BM+256][64] bf16, XOR-swizzled: chunk (row,slot) holds
// global (row, slot^(row&7)) [slot = 8-elem group]. Counted vmcnt, raw barriers.

__device__ __forceinline__ short8 ld_sw(const short* base, int row, int k8){
    return *(const short8*)(base + row*64 + ((k8 ^ (row & 7)) << 3));
}

template<int MT>
__device__ __forceinline__ void stage_tile(const bf16* __restrict__ Ag,
                                           const bf16* __restrict__ Bg,
                                           int K, size_t bm, size_t bn, int t,
                                           short* buf){
    constexpr int BM = MT*32;
    constexpr int L = (BM + 256)/64;     // gl16 per thread per tile
    const int tid = threadIdx.x;
    const int wid = tid >> 6;
    #pragma unroll
    for (int i = 0; i < L; i++){
        int cidx = i*512 + tid;
        int row = cidx >> 3, slot = cidx & 7;
        int k8 = slot ^ (row & 7);
        const bf16* src = (row < BM)
            ? Ag + (bm + row) * (size_t)K + t*64 + k8*8
            : Bg + (bn + row - BM) * (size_t)K + t*64 + k8*8;
        gl16(src, buf + (size_t)(i*512 + wid*64)*8);   // linear dest, wave-uniform base
    }
}

template<int MT>
__device__ __forceinline__ void compute_tile(const short* buf, f32x4 (&acc)[MT][4],
                                             int wm, int wn, int fr, int fk8){
    constexpr int BM = MT*32;
    const short* A = buf;
    const short* B = buf + BM*64;
    short8 a[4][2], b0[2][2], b1[2][2];
    // P0: A row-half 0 + B col-half 0; quad (r0, c0)
    #pragma unroll
    for (int m = 0; m < 4; m++)
        #pragma unroll
        for (int kk = 0; kk < 2; kk++)
            a[m][kk] = ld_sw(A, wm*(MT*16) + m*16 + fr, fk8 + kk*4);
    #pragma unroll
    for (int n = 0; n < 2; n++)
        #pragma unroll
        for (int kk = 0; kk < 2; kk++)
            b0[n][kk] = ld_sw(B, wn*64 + n*16 + fr, fk8 + kk*4);
    __builtin_amdgcn_s_setprio(1);
    #pragma unroll
    for (int m = 0; m < 4; m++)
        #pragma unroll
        for (int n = 0; n < 2; n++)
            #pragma unroll
            for (int kk = 0; kk < 2; kk++)
                acc[m][n] = __builtin_amdgcn_mfma_f32_16x16x32_bf16(a[m][kk], b0[n][kk], acc[m][n], 0, 0, 0);
    __builtin_amdgcn_s_setprio(0);
    // P1: B col-half 1; quad (r0, c1)
    #pragma unroll
    for (int n = 0; n < 2; n++)
        #pragma unroll
        for (int kk = 0; kk < 2; kk++)
            b1[n][kk] = ld_sw(B, wn*64 + (n+2)*16 + fr, fk8 + kk*4);
    __builtin_amdgcn_s_setprio(1);
    #pragma unroll
    for (int m = 0; m < 4; m++)
        #pragma unroll
        for (int n = 0; n < 2; n++)
            #pragma unroll
            for (int kk = 0; kk < 2; kk++)
                acc[m][n+2] = __builtin_amdgcn_mfma_f32_16x16x32_bf16(a[m][kk], b1[n][kk], acc[m][n+2], 0, 0, 0);
    __builtin_amdgcn_s_setprio(0);
    if constexpr (MT == 8){
        // P2: A row-half 1; quad (r1, c1)
        #pragma unroll
        for (int m = 0; m < 4; m++)
            #pragma unroll
            for (int kk = 0; kk < 2; kk++)
                a[m][kk] = ld_sw(A, wm*128 + (4+m)*16 + fr, fk8 + kk*4);
        __builtin_amdgcn_s_setprio(1);
        #pragma unroll
        for (int m = 0; m < 4; m++)
            #pragma unroll
            for (int n = 0; n < 2; n++)
                #pragma unroll
                for (int kk = 0; kk < 2; kk++)
                    acc[4+m][n+2] = __builtin_amdgcn_mfma_f32_16x16x32_bf16(a[m][kk], b1[n][kk], acc[4+m][n+2], 0, 0, 0);
        __builtin_amdgcn_s_setprio(0);
        // P3: quad (r1, c0)
        __builtin_amdgcn_s_setprio(1);
        #pragma unroll
        for (int m = 0; m < 4; m++)
            #pragma unroll
            for (int n = 0; n < 2; n++)
                #pragma unroll
                for (int kk = 0; kk < 2; kk++)
                    acc[4+m][n] = __builtin_amdgcn_mfma_f32_16x16x32_bf16(a[m][kk], b0[n][kk], acc[4+m][n], 0, 0, 0);
        __builtin_amdgcn_s_setprio(0);
    }
}

template<int MT>
__device__ __forceinline__ void gemm8p_main(const bf16* __restrict__ Ag,
                                            const bf16* __restrict__ Bg,
                                            int K, size_t bm, size_t bn,
                                            short* lds, f32x4 (&acc)[MT][4]){
    constexpr int BM = MT*32;
    constexpr int TILE = (BM + 256)*64;   // shorts per buffer
    const int NTk = K >> 6;
    const int lane = threadIdx.x & 63;
    const int wid = threadIdx.x >> 6;
    const int wm = wid >> 2, wn = wid & 3;
    const int fr = lane & 15, fk8 = lane >> 4;
    // prologue: stage tiles 0,1
    stage_tile<MT>(Ag, Bg, K, bm, bn, 0, lds);
    stage_tile<MT>(Ag, Bg, K, bm, bn, 1, lds + TILE);
    if constexpr (MT == 8) asm volatile("s_waitcnt vmcnt(8)" ::: "memory");
    else                   asm volatile("s_waitcnt vmcnt(6)" ::: "memory");
    __builtin_amdgcn_sched_barrier(0);
    __builtin_amdgcn_s_barrier();
    __builtin_amdgcn_sched_barrier(0);
    for (int t = 0; t < NTk; t++){
        short* buf = lds + (t & 1)*TILE;
        compute_tile<MT>(buf, acc, wm, wn, fr, fk8);
        __builtin_amdgcn_sched_barrier(0);
        __builtin_amdgcn_s_barrier();          // B1: all reads of buf done
        if (t + 2 < NTk){
            stage_tile<MT>(Ag, Bg, K, bm, bn, t+2, buf);
            if constexpr (MT == 8) asm volatile("s_waitcnt vmcnt(8)" ::: "memory");
            else                   asm volatile("s_waitcnt vmcnt(6)" ::: "memory");
        } else if (t + 1 < NTk){
            asm volatile("s_waitcnt vmcnt(0)" ::: "memory");
        }
        __builtin_amdgcn_sched_barrier(0);
        __builtin_amdgcn_s_barrier();          // B2: tile t+1 resident for all waves
        __builtin_amdgcn_sched_barrier(0);
    }
}

// ---------------- GEMM1: hn[8192x1024] x W_in[5376x1024]^T, segmented epilogue ----------------
__global__ __launch_bounds__(512, 2) void k_gemm1_8p(const bf16* __restrict__ A,
                                                     const bf16* __restrict__ B,
                                                     bf16* __restrict__ z,
                                                     bf16* __restrict__ xp,
                                                     bf16* __restrict__ Bc,
                                                     bf16* __restrict__ Cc,
                                                     float* __restrict__ dtr){
    extern __shared__ short lds[];
    int wg = (blockIdx.x & 7)*84 + (blockIdx.x >> 3);   // 672 blocks, XCD swizzle
    size_t bm = (size_t)(wg / 21) * 256;
    size_t bn = (size_t)(wg % 21) * 256;
    f32x4 acc[8][4] = {};
    gemm8p_main<8>(A, B, D_MODEL, bm, bn, lds, acc);
    const int lane = threadIdx.x & 63;
    const int wid = threadIdx.x >> 6;
    const int wm = wid >> 2, wn = wid & 3;
    int cr = (lane >> 4)*4, cc = lane & 15;
    #pragma unroll
    for (int m = 0; m < 8; m++){
        size_t r0 = bm + wm*128 + m*16 + cr;
        #pragma unroll
        for (int n = 0; n < 4; n++){
            int c = (int)bn + wn*64 + n*16 + cc;
            #pragma unroll
            for (int j = 0; j < 4; j++){
                float v = acc[m][n][j];
                size_t r = r0 + j;
                if (c < O1)            z  [r * D_INNER + c]        = f2b(v);
                else if (c < O2)       xp [r * D_INNER + (c - O1)] = f2b(v);
                else if (c < O3)       Bc [r * 512 + (c - O2)]     = f2b(v);
                else if (c < O4)       Cc [r * 512 + (c - O3)]     = f2b(v);
                else if (c < PROJ_N)   dtr[r * 8 + (c - O4)]       = v;
            }
        }
    }
}

// ---------------- GEMM2: yn[8192x2048] x W_out[1024x2048]^T + hidden -> f32 ----------------
__global__ __launch_bounds__(512, 2) void k_gemm2_8p(const bf16* __restrict__ A,
                                                     const bf16* __restrict__ B,
                                                     const float* __restrict__ res,
                                                     float* __restrict__ C){
    extern __shared__ short lds[];
    int wg = (blockIdx.x & 7)*32 + (blockIdx.x >> 3);   // 256 blocks
    size_t bm = (size_t)(wg / 4) * 128;
    size_t bn = (size_t)(wg % 4) * 256;
    f32x4 acc[4][4] = {};
    gemm8p_main<4>(A, B, D_INNER, bm, bn, lds, acc);
    const int lane = threadIdx.x & 63;
    const int wid = threadIdx.x >> 6;
    const int wm = wid >> 2, wn = wid & 3;
    int cr = (lane >> 4)*4, cc = lane & 15;
    #pragma unroll
    for (int m = 0; m < 4; m++){
        size_t r0 = bm + wm*64 + m*16 + cr;
        #pragma unroll
        for (int n = 0; n < 4; n++){
            size_t c = bn + wn*64 + n*16 + cc;
            #pragma unroll
            for (int j = 0; j < 4; j++){
                size_t r = r0 + j;
                C[r * D_MODEL + c] = acc[m][n][j] + res[r * D_MODEL + c];
            }
        }
    }
}

// ---------------- depthwise causal conv(4) + SiLU ----------------
__global__ __launch_bounds__(256) void k_conv_silu(const bf16* __restrict__ xp,
                                                   const float* __restrict__ cw,
                                                   const float* __restrict__ cb,
                                                   bf16* __restrict__ xout){
    int b = blockIdx.x;
    int c = blockIdx.y * 256 + threadIdx.x;
    float w0 = cw[c*4+0], w1 = cw[c*4+1], w2 = cw[c*4+2], w3 = cw[c*4+3];
    float bias = cb[c];
    const bf16* ib = xp + (size_t)b * SEQ * D_INNER + c;
    bf16* ob = xout + (size_t)b * SEQ * D_INNER + c;
    float x0 = 0.f, x1 = 0.f, x2 = 0.f;
    for (int s = 0; s < SEQ; s++){
        float x3 = b2f(ib[(size_t)s * D_INNER]);
        float a = x0*w0 + x1*w1 + x2*w2 + x3*w3 + bias;
        ob[(size_t)s * D_INNER] = f2b(silu_f(a));
        x0 = x1; x1 = x2; x2 = x3;
    }
}

// ---------------- precompute Wm (8x8), bm (8), A (8) ----------------
__global__ __launch_bounds__(64) void k_prep(const float* __restrict__ W_dt,
                                             const float* __restrict__ b_dt,
                                             const float* __restrict__ A_log,
                                             float* __restrict__ misc){
    int t = threadIdx.x;
    int h = t >> 3, k = t & 7;
    float s = 0.f;
    for (int d = 0; d < HEAD_DIM; d++) s += W_dt[(size_t)(h*HEAD_DIM + d) * N_HEADS + k];
    misc[t] = s * (1.0f/(float)HEAD_DIM);
    if (t < 8){
        float sb = 0.f;
        for (int d = 0; d < HEAD_DIM; d++) sb += b_dt[t*HEAD_DIM + d];
        misc[64 + t] = sb * (1.0f/(float)HEAD_DIM);
        misc[72 + t] = -expf(A_log[t]);
    }
}

// ---------------- dt_h -> logA cumsum (lcs) + tdec ----------------
__global__ __launch_bounds__(64) void k_dt_lcs(const float* __restrict__ dtr,
                                               const float* __restrict__ misc,
                                               float* __restrict__ lcs,
                                               float* __restrict__ tdec){
    __shared__ float sm[80];
    __shared__ float la[CHUNK][N_HEADS];
    int bc = blockIdx.x;
    int l = threadIdx.x;
    for (int i = l; i < 80; i += 64) sm[i] = misc[i];
    __syncthreads();
    const float* dr = dtr + (size_t)(bc*CHUNK + l) * 8;
    float d0 = dr[0], d1 = dr[1], d2 = dr[2], d3 = dr[3];
    float d4 = dr[4], d5 = dr[5], d6 = dr[6], d7 = dr[7];
    #pragma unroll
    for (int h = 0; h < 8; h++){
        float dt = sm[64+h]
                 + d0*sm[h*8+0] + d1*sm[h*8+1] + d2*sm[h*8+2] + d3*sm[h*8+3]
                 + d4*sm[h*8+4] + d5*sm[h*8+5] + d6*sm[h*8+6] + d7*sm[h*8+7];
        float sp = (dt > 20.f) ? dt : log1pf(expf(dt));
        la[l][h] = sp * sm[72+h];
    }
    __syncthreads();
    float out[8];
    #pragma unroll
    for (int h = 0; h < 8; h++) out[h] = 0.f;
    for (int l2 = 0; l2 <= l; l2++){
        #pragma unroll
        for (int h = 0; h < 8; h++) out[h] += la[l2][h];
    }
    float* lo = lcs + (size_t)(bc*CHUNK + l) * N_HEADS;
    #pragma unroll
    for (int h = 0; h < 8; h++) lo[h] = out[h];
    if (l == 63){
        #pragma unroll
        for (int h = 0; h < 8; h++) tdec[bc*N_HEADS + h] = expf(out[h]);
    }
}

// ================= fused chunked SSM (round-4, verified) =================
#define LB   0
#define LC   4096
#define LGM  8192
#define LXT  12800
#define LSH  29184
#define LF   45568
#define LDS_BYTES 91904

__device__ __forceinline__ short8 frag_sw(const short* arr, int r, int k){
    return *(const short8*)(arr + r*64 + (k ^ ((r&7)<<3)));
}

__global__ __launch_bounds__(256, 1) void k_ssm(const bf16* __restrict__ Bc,
                                                const bf16* __restrict__ Cc,
                                                bf16* xg,
                                                const float* __restrict__ lcs,
                                                const float* __restrict__ tdec,
                                                const float* __restrict__ Dv){
    extern __shared__ short lds[];
    short* Blds  = lds + LB;
    short* Clds  = lds + LC;
    short* GMlds = lds + LGM;
    short* XTlds = lds + LXT;
    short* Shr   = lds + LSH;
    float* el = (float*)(lds + LF);
    float* ml = el + 64;
    float* ee = el + 128;

    const int tid = threadIdx.x;
    const int lane = tid & 63;
    const int wid = tid >> 6;
    const int fr = lane & 15;
    const int fk = (lane >> 4) * 8;
    const int r0 = (lane >> 4) * 4;
    const int b = blockIdx.x >> 3, h = blockIdx.x & 7;
    const float Dh = Dv[h];

    f32x4 carry[4][4] = {};

    for (int c = 0; c < NCHUNK; c++){
        const int bc = b*NCHUNK + c;
        __syncthreads();
        #pragma unroll
        for (int i = 0; i < 2; i++){
            int slot = i*256 + tid;
            int s = slot >> 3, u = slot & 7;
            size_t rb = (size_t)(bc*CHUNK + s) * 512 + h*64 + ((u ^ (s&7)) * 8);
            gl16(Bc + rb, Blds + slot*8);
            gl16(Cc + rb, Clds + slot*8);
        }
        #pragma unroll
        for (int i = 0; i < 8; i++){
            int slot = i*256 + tid;
            int s = slot >> 5, ck = slot & 31;
            gl16(xg + (size_t)(bc*CHUNK + s) * D_INNER + h*HEAD_DIM + ck*8, Shr + slot*8);
        }
        if (tid < 64) el[tid] = lcs[(size_t)(bc*CHUNK + tid) * N_HEADS + h];
        __syncthreads();
        if (tid < 64){
            float e63 = el[63];
            ml[tid] = expf(e63 - el[tid]);
            ee[tid] = expf(el[tid]);
        }
        #pragma unroll
        for (int i = 0; i < 8; i++){
            short8 t8;
            #pragma unroll
            for (int j = 0; j < 8; j++) t8[j] = Shr[(i*8 + j)*HEAD_DIM + tid];
            *(short8*)(XTlds + tid*64 + ((i*8) ^ ((tid&7)<<3))) = t8;
        }
        __syncthreads();
        {
            f32x4 accg[4] = {};
            #pragma unroll
            for (int kk = 0; kk < 2; kk++){
                short8 a = frag_sw(Clds, wid*16 + fr, kk*32 + fk);
                #pragma unroll
                for (int nt = 0; nt < 4; nt++){
                    short8 bb = frag_sw(Blds, nt*16 + fr, kk*32 + fk);
                    accg[nt] = __builtin_amdgcn_mfma_f32_16x16x32_bf16(a, bb, accg[nt], 0, 0, 0);
                }
            }
            #pragma unroll
            for (int nt = 0; nt < 4; nt++){
                int s = nt*16 + fr;
                float els = el[s];
                #pragma unroll
                for (int j = 0; j < 4; j++){
                    int l = wid*16 + r0 + j;
                    float f = (s <= l) ? expf(el[l] - els) : 0.f;
                    GMlds[l*72 + s] = f2s(accg[nt][j] * f);
                }
            }
            int crow = wid*16 + (lane >> 2), cq = lane & 3;
            float fe = ee[crow];
            #pragma unroll
            for (int half = 0; half < 2; half++){
                short8 v = *(short8*)(Clds + crow*64 + cq*16 + half*8);
                #pragma unroll
                for (int j = 0; j < 8; j++) v[j] = f2s(s2f(v[j]) * fe);
                *(short8*)(Clds + crow*64 + cq*16 + half*8) = v;
            }
        }
        #pragma unroll
        for (int mt = 0; mt < 4; mt++)
            #pragma unroll
            for (int nt = 0; nt < 4; nt++)
                #pragma unroll
                for (int j = 0; j < 4; j++){
                    int d = wid*64 + mt*16 + r0 + j;
                    int n = nt*16 + fr;
                    Shr[d*64 + (n ^ ((d&7)<<3))] = f2s(carry[mt][nt][j]);
                }
        float btv[16];
        {
            int bn_ = tid & 63, bq = tid >> 6;
            #pragma unroll
            for (int i = 0; i < 16; i++){
                int s = bq*16 + i;
                btv[i] = s2f(Blds[s*64 + (bn_ ^ ((s&7)<<3))]) * ml[s];
            }
        }
        __syncthreads();
        {
            int bn_ = tid & 63, bq = tid >> 6;
            #pragma unroll
            for (int i = 0; i < 16; i++){
                int s = bq*16 + i;
                Blds[bn_*64 + (s ^ ((bn_&7)<<3))] = f2s(btv[i]);
            }
        }
        {
            f32x4 accy[4][4] = {};
            #pragma unroll
            for (int kk = 0; kk < 2; kk++){
                short8 ag[4], ae[4], bx[4], bh[4];
                #pragma unroll
                for (int mt = 0; mt < 4; mt++){
                    ag[mt] = *(const short8*)(GMlds + (mt*16 + fr)*72 + kk*32 + fk);
                    ae[mt] = frag_sw(Clds, mt*16 + fr, kk*32 + fk);
                }
                #pragma unroll
                for (int nt = 0; nt < 4; nt++){
                    int d = wid*64 + nt*16 + fr;
                    bx[nt] = frag_sw(XTlds, d, kk*32 + fk);
                    bh[nt] = frag_sw(Shr,  d, kk*32 + fk);
                }
                #pragma unroll
                for (int mt = 0; mt < 4; mt++)
                    #pragma unroll
                    for (int nt = 0; nt < 4; nt++){
                        accy[mt][nt] = __builtin_amdgcn_mfma_f32_16x16x32_bf16(ag[mt], bx[nt], accy[mt][nt], 0, 0, 0);
                        accy[mt][nt] = __builtin_amdgcn_mfma_f32_16x16x32_bf16(ae[mt], bh[nt], accy[mt][nt], 0, 0, 0);
                    }
            }
            #pragma unroll
            for (int mt = 0; mt < 4; mt++)
                #pragma unroll
                for (int nt = 0; nt < 4; nt++){
                    int d = wid*64 + nt*16 + fr;
                    #pragma unroll
                    for (int j = 0; j < 4; j++){
                        int l = mt*16 + r0 + j;
                        float xv = s2f(XTlds[d*64 + (l ^ ((d&7)<<3))]);
                        xg[(size_t)(bc*CHUNK + l) * D_INNER + h*HEAD_DIM + d] = f2b(accy[mt][nt][j] + xv*Dh);
                    }
                }
        }
        __syncthreads();
        {
            f32x4 accs[4][4] = {};
            #pragma unroll
            for (int kk = 0; kk < 2; kk++){
                short8 ax[4], bt[4];
                #pragma unroll
                for (int mt = 0; mt < 4; mt++)
                    ax[mt] = frag_sw(XTlds, wid*64 + mt*16 + fr, kk*32 + fk);
                #pragma unroll
                for (int nt = 0; nt < 4; nt++)
                    bt[nt] = frag_sw(Blds, nt*16 + fr, kk*32 + fk);
                #pragma unroll
                for (int mt = 0; mt < 4; mt++)
                    #pragma unroll
                    for (int nt = 0; nt < 4; nt++)
                        accs[mt][nt] = __builtin_amdgcn_mfma_f32_16x16x32_bf16(ax[mt], bt[nt], accs[mt][nt], 0, 0, 0);
            }
            float td = tdec[bc*N_HEADS + h];
            #pragma unroll
            for (int mt = 0; mt < 4; mt++)
                #pragma unroll
                for (int nt = 0; nt < 4; nt++)
                    carry[mt][nt] = td * carry[mt][nt] + accs[mt][nt];
        }
    }
}

// ---------------- gate with silu(z) + RMSNorm (output) -> yn bf16 ----------------
__global__ __launch_bounds__(256) void k_gate_rms(const bf16* __restrict__ y,
                                                  const bf16* __restrict__ z,
                                                  const float* __restrict__ g,
                                                  bf16* __restrict__ yn){
    int row = blockIdx.x, t = threadIdx.x;
    union { uint4 u; bf16 b[8]; } yv, zv, ov;
    yv.u = ((const uint4*)(y + (size_t)row * D_INNER))[t];
    zv.u = ((const uint4*)(z + (size_t)row * D_INNER))[t];
    float v[8];
    float ss = 0.f;
    #pragma unroll
    for (int i = 0; i < 8; i++){
        float a = b2f(yv.b[i]);
        float q = b2f(zv.b[i]);
        v[i] = a * silu_f(q);
        ss += v[i]*v[i];
    }
    ss = block_sum_256(ss);
    float sc = rsqrtf(ss * (1.0f/(float)D_INNER) + EPSF);
    const float4* g4 = (const float4*)g;
    float4 ga = g4[2*t], gb = g4[2*t+1];
    float gg[8] = {ga.x,ga.y,ga.z,ga.w,gb.x,gb.y,gb.z,gb.w};
    #pragma unroll
    for (int i = 0; i < 8; i++) ov.b[i] = f2b(v[i]*sc*gg[i]);
    ((uint4*)(yn + (size_t)row * D_INNER))[t] = ov.u;
}

extern "C" void kernel_launch(void* const* d_in, const int* in_sizes, int n_in,
                              void* d_out, int out_size, void* d_ws, size_t ws_size,
                              hipStream_t stream){
    const float* hidden = (const float*)d_in[0];
    const float* W_in   = (const float*)d_in[1];
    const float* conv_w = (const float*)d_in[2];
    const float* conv_b = (const float*)d_in[3];
    const float* W_dt   = (const float*)d_in[4];
    const float* b_dt   = (const float*)d_in[5];
    const float* A_log  = (const float*)d_in[6];
    const float* Dv     = (const float*)d_in[7];
    const float* W_out  = (const float*)d_in[8];
    const float* g_in   = (const float*)d_in[9];
    const float* g_out  = (const float*)d_in[10];

    // workspace layout (bytes) — total ~139.0 MiB
    char* ws = (char*)d_ws;
    bf16*  z    = (bf16*)(ws + 0);            // 33,554,432
    bf16*  xp   = (bf16*)(ws + 33554432);     // 33,554,432 (reused as yn)
    bf16*  x    = (bf16*)(ws + 67108864);     // 33,554,432 (y in place via k_ssm)
    bf16*  Bc   = (bf16*)(ws + 100663296);    //  8,388,608
    bf16*  Cc   = (bf16*)(ws + 109051904);    //  8,388,608
    float* dtr  = (float*)(ws + 117440512);   //    262,144
    float* lcs  = (float*)(ws + 117702656);   //    262,144
    float* tdec = (float*)(ws + 117964800);   //      4,096
    float* misc = (float*)(ws + 117968896);   //        512
    bf16*  Wb   = (bf16*)(ws + 117969408);    // 11,010,048 (W_in_b 5376x1024; later W_out_b)
    bf16*  hnb  = (bf16*)(ws + 128979456);    // 16,777,216
    bf16*  yn   = xp;

    k_rms_in<<<ROWS, 256, 0, stream>>>(hidden, g_in, hnb);
    k_cvt_pad<<<(PROJ_NPAD*D_MODEL/4 + 255)/256, 256, 0, stream>>>(W_in, Wb, PROJ_N*D_MODEL, PROJ_NPAD*D_MODEL);
    hipFuncSetAttribute((const void*)k_gemm1_8p, hipFuncAttributeMaxDynamicSharedMemorySize, 131072);
    k_gemm1_8p<<<(ROWS/256)*(PROJ_NPAD/256), 512, 131072, stream>>>(hnb, Wb, z, xp, Bc, Cc, dtr);
    k_conv_silu<<<dim3(BATCH, D_INNER/256), 256, 0, stream>>>(xp, conv_w, conv_b, x);
    k_prep<<<1, 64, 0, stream>>>(W_dt, b_dt, A_log, misc);
    k_dt_lcs<<<BATCH*NCHUNK, 64, 0, stream>>>(dtr, misc, lcs, tdec);
    hipFuncSetAttribute((const void*)k_ssm, hipFuncAttributeMaxDynamicSharedMemorySize, LDS_BYTES);
    k_ssm<<<BATCH*N_HEADS, 256, LDS_BYTES, stream>>>(Bc, Cc, x, lcs, tdec, Dv);
    k_gate_rms<<<ROWS, 256, 0, stream>>>(x, z, g_out, yn);
    k_cvt_pad<<<(D_MODEL*D_INNER/4 + 255)/256, 256, 0, stream>>>(W_out, Wb, D_MODEL*D_INNER, D_MODEL*D_INNER);
    hipFuncSetAttribute((const void*)k_gemm2_8p, hipFuncAttributeMaxDynamicSharedMemorySize, 98304);
    k_gemm2_8p<<<(ROWS/128)*(D_MODEL/256), 512, 98304, stream>>>(yn, Wb, hidden, (float*)d_out);
}

// Round 6
// 343.537 us; speedup vs baseline: 8.1705x; 1.0249x over previous
//
#include <hip/hip_runtime.h>
#include <hip/hip_bf16.h>
#include <math.h>

typedef __hip_bfloat16 bf16;
typedef __attribute__((ext_vector_type(8))) short short8;
typedef __attribute__((ext_vector_type(4))) float f32x4;

#define AS1 __attribute__((address_space(1)))
#define AS3 __attribute__((address_space(3)))

#define D_MODEL 1024
#define D_INNER 2048
#define N_HEADS 8
#define D_STATE 64
#define CHUNK 64
#define HEAD_DIM 256
#define NCHUNK 4
#define BATCH 32
#define SEQ 256
#define ROWS (BATCH*SEQ)          // 8192
#define PROJ_N 5128
#define PROJ_NPAD 5376            // 21 tiles of 256
#define O1 D_INNER                // 2048
#define O2 (2*D_INNER)            // 4096
#define O3 (O2 + N_HEADS*D_STATE) // 4608
#define O4 (O3 + N_HEADS*D_STATE) // 5120
#define EPSF 1.1920929e-07f

__device__ __forceinline__ float silu_f(float x){ return x / (1.0f + expf(-x)); }
__device__ __forceinline__ float b2f(bf16 v){ return __bfloat162float(v); }
__device__ __forceinline__ bf16  f2b(float v){ return __float2bfloat16(v); }
__device__ __forceinline__ short f2s(float v){ bf16 b = __float2bfloat16(v); union{bf16 b; short s;} u; u.b=b; return u.s; }
__device__ __forceinline__ float s2f(short v){ union{short s; bf16 b;} u; u.s=v; return __bfloat162float(u.b); }

__device__ __forceinline__ void gl16(const void* g, void* l){
    __builtin_amdgcn_global_load_lds((const AS1 void*)g, (AS3 void*)l, 16, 0, 0);
}

__device__ __forceinline__ float block_sum_256(float v){
    __shared__ float sm[4];
    #pragma unroll
    for (int o = 32; o > 0; o >>= 1) v += __shfl_down(v, o, 64);
    int lane = threadIdx.x & 63, w = threadIdx.x >> 6;
    if (lane == 0) sm[w] = v;
    __syncthreads();
    return sm[0] + sm[1] + sm[2] + sm[3];
}

// ---------------- RMSNorm (input) -> bf16 ----------------
__global__ __launch_bounds__(256) void k_rms_in(const float* __restrict__ x,
                                                const float* __restrict__ g,
                                                bf16* __restrict__ out){
    int row = blockIdx.x, t = threadIdx.x;
    const float4* xr = (const float4*)(x + (size_t)row * D_MODEL);
    float4 v = xr[t];
    float ss = v.x*v.x + v.y*v.y + v.z*v.z + v.w*v.w;
    ss = block_sum_256(ss);
    float sc = rsqrtf(ss * (1.0f/(float)D_MODEL) + EPSF);
    float4 gv = ((const float4*)g)[t];
    union { ushort4 u; bf16 b[4]; } o;
    o.b[0] = f2b(v.x*sc*gv.x); o.b[1] = f2b(v.y*sc*gv.y);
    o.b[2] = f2b(v.z*sc*gv.z); o.b[3] = f2b(v.w*sc*gv.w);
    ((ushort4*)(out + (size_t)row * D_MODEL))[t] = o.u;
}

// ---------------- f32 -> bf16 cast with zero-pad tail ----------------
__global__ __launch_bounds__(256) void k_cvt_pad(const float* __restrict__ in,
                                                 bf16* __restrict__ out,
                                                 int n_in, int n_out){
    int i = (blockIdx.x * 256 + threadIdx.x) * 4;
    if (i >= n_out) return;
    union { ushort4 u; bf16 b[4]; } o;
    if (i + 3 < n_in){
        float4 v = *(const float4*)(in + i);
        o.b[0]=f2b(v.x); o.b[1]=f2b(v.y); o.b[2]=f2b(v.z); o.b[3]=f2b(v.w);
    } else {
        #pragma unroll
        for (int j = 0; j < 4; j++) o.b[j] = f2b((i+j < n_in) ? in[i+j] : 0.f);
    }
    *(ushort4*)(out + i) = o.u;
}

// ================= ring-4 deep-pipelined NT GEMM, BK=32 =================
// A [M][K], B [N][K] bf16. Superblock = BM rows of A then 256 rows of B.
// LDS tile [SUP/2 superrows][8 x 16B slots], XOR-swizzled: LDS slot
// (srow, s8) holds global (srow*2 + ((s8^(srow&7))>>2), 16B-col (s8^(srow&7))&3).
// 64 lanes reading a column-slice hit each bank exactly 2x (free).
// Ring of 4 buffers; stage tile t+3 during tile t; vmcnt keeps 2 tiles in flight.

__device__ __forceinline__ short8 ld32(const short* base, int row, int g){
    int sr = row >> 1;
    int e8 = (((row & 1) << 2) | g) ^ (sr & 7);
    return *(const short8*)(base + sr*64 + e8*8);
}

template<int MT>
__device__ __forceinline__ void stage_j(const bf16* __restrict__ Ag,
                                        const bf16* __restrict__ Bg,
                                        int K, size_t bm, size_t bn, int t,
                                        short* buf, int j){
    constexpr int BM = MT*32;
    const int tid = threadIdx.x;
    const int wid = tid >> 6;
    int cidx = j*512 + tid;
    int srow = cidx >> 3, s8 = cidx & 7;
    int eff = s8 ^ (srow & 7);
    int grow = srow*2 + (eff >> 2);
    int gcol = t*32 + (eff & 3)*8;
    const bf16* src = (grow < BM)
        ? Ag + (bm + grow) * (size_t)K + gcol
        : Bg + (bn + grow - BM) * (size_t)K + gcol;
    gl16(src, buf + (size_t)(j*512 + wid*64)*8);   // wave-uniform base + lane*16B
}

template<int MT>
__device__ __forceinline__ void gemm_ring4(const bf16* __restrict__ Ag,
                                           const bf16* __restrict__ Bg,
                                           int K, size_t bm, size_t bn,
                                           short* lds, f32x4 (&acc)[MT][4]){
    constexpr int BM = MT*32;
    constexpr int TILE = (BM + 256)*32;    // shorts per buffer
    constexpr int LPT  = (BM + 256)/128;   // gl16 per thread per tile (4 or 3)
    const int NT = K >> 5;
    const int lane = threadIdx.x & 63;
    const int wm = (threadIdx.x >> 6) >> 2, wn = (threadIdx.x >> 6) & 3;
    const int fr = lane & 15, g = lane >> 4;

    // prologue: stage tiles 0,1,2; require tile 0 resident (2 tiles may fly)
    #pragma unroll
    for (int p = 0; p < 3; p++)
        #pragma unroll
        for (int j = 0; j < LPT; j++)
            stage_j<MT>(Ag, Bg, K, bm, bn, p, lds + p*TILE, j);
    if constexpr (MT == 8) asm volatile("s_waitcnt vmcnt(8)" ::: "memory");
    else                   asm volatile("s_waitcnt vmcnt(6)" ::: "memory");
    __builtin_amdgcn_sched_barrier(0);
    __builtin_amdgcn_s_barrier();
    __builtin_amdgcn_sched_barrier(0);

    for (int t = 0; t < NT; t++){
        short* buf = lds + (t & 3)*TILE;
        short* Bb  = buf + BM*32;
        short* stg = lds + ((t+3) & 3)*TILE;
        const bool ds = (t+3 < NT);
        if constexpr (MT == 8){
            short8 a[4], b[4];
            #pragma unroll
            for (int m = 0; m < 4; m++) a[m] = ld32(buf, wm*128 + m*16 + fr, g);
            #pragma unroll
            for (int n = 0; n < 4; n++) b[n] = ld32(Bb, wn*64 + n*16 + fr, g);
            if (ds){ stage_j<MT>(Ag,Bg,K,bm,bn,t+3,stg,0); stage_j<MT>(Ag,Bg,K,bm,bn,t+3,stg,1); }
            __builtin_amdgcn_s_setprio(1);
            #pragma unroll
            for (int m = 0; m < 4; m++)
                #pragma unroll
                for (int n = 0; n < 4; n++)
                    acc[m][n] = __builtin_amdgcn_mfma_f32_16x16x32_bf16(a[m], b[n], acc[m][n], 0, 0, 0);
            __builtin_amdgcn_s_setprio(0);
            __builtin_amdgcn_sched_barrier(0);
            __builtin_amdgcn_s_barrier();
            __builtin_amdgcn_sched_barrier(0);
            short8 a2[4];
            #pragma unroll
            for (int m = 0; m < 4; m++) a2[m] = ld32(buf, wm*128 + 64 + m*16 + fr, g);
            if (ds){ stage_j<MT>(Ag,Bg,K,bm,bn,t+3,stg,2); stage_j<MT>(Ag,Bg,K,bm,bn,t+3,stg,3); }
            __builtin_amdgcn_s_setprio(1);
            #pragma unroll
            for (int m = 0; m < 4; m++)
                #pragma unroll
                for (int n = 0; n < 4; n++)
                    acc[4+m][n] = __builtin_amdgcn_mfma_f32_16x16x32_bf16(a2[m], b[n], acc[4+m][n], 0, 0, 0);
            __builtin_amdgcn_s_setprio(0);
        } else {
            short8 a[4], b[2];
            #pragma unroll
            for (int m = 0; m < 4; m++) a[m] = ld32(buf, wm*64 + m*16 + fr, g);
            #pragma unroll
            for (int n = 0; n < 2; n++) b[n] = ld32(Bb, wn*64 + n*16 + fr, g);
            if (ds){ stage_j<MT>(Ag,Bg,K,bm,bn,t+3,stg,0); stage_j<MT>(Ag,Bg,K,bm,bn,t+3,stg,1); }
            __builtin_amdgcn_s_setprio(1);
            #pragma unroll
            for (int m = 0; m < 4; m++)
                #pragma unroll
                for (int n = 0; n < 2; n++)
                    acc[m][n] = __builtin_amdgcn_mfma_f32_16x16x32_bf16(a[m], b[n], acc[m][n], 0, 0, 0);
            __builtin_amdgcn_s_setprio(0);
            __builtin_amdgcn_sched_barrier(0);
            __builtin_amdgcn_s_barrier();
            __builtin_amdgcn_sched_barrier(0);
            short8 b1[2];
            #pragma unroll
            for (int n = 0; n < 2; n++) b1[n] = ld32(Bb, wn*64 + (n+2)*16 + fr, g);
            if (ds) stage_j<MT>(Ag,Bg,K,bm,bn,t+3,stg,2);
            __builtin_amdgcn_s_setprio(1);
            #pragma unroll
            for (int m = 0; m < 4; m++)
                #pragma unroll
                for (int n = 0; n < 2; n++)
                    acc[m][n+2] = __builtin_amdgcn_mfma_f32_16x16x32_bf16(a[m], b1[n], acc[m][n+2], 0, 0, 0);
            __builtin_amdgcn_s_setprio(0);
        }
        __builtin_amdgcn_sched_barrier(0);
        if constexpr (MT == 8){
            if (t+3 < NT)      asm volatile("s_waitcnt vmcnt(8)" ::: "memory");
            else if (t+2 < NT) asm volatile("s_waitcnt vmcnt(4)" ::: "memory");
            else if (t+1 < NT) asm volatile("s_waitcnt vmcnt(0)" ::: "memory");
        } else {
            if (t+3 < NT)      asm volatile("s_waitcnt vmcnt(6)" ::: "memory");
            else if (t+2 < NT) asm volatile("s_waitcnt vmcnt(3)" ::: "memory");
            else if (t+1 < NT) asm volatile("s_waitcnt vmcnt(0)" ::: "memory");
        }
        __builtin_amdgcn_sched_barrier(0);
        __builtin_amdgcn_s_barrier();
        __builtin_amdgcn_sched_barrier(0);
    }
}

// ---------------- GEMM1: hn[8192x1024] x W_in[5376x1024]^T, segmented epilogue ----------------
__global__ __launch_bounds__(512, 2) void k_gemm1_r4(const bf16* __restrict__ A,
                                                     const bf16* __restrict__ B,
                                                     bf16* __restrict__ z,
                                                     bf16* __restrict__ xp,
                                                     bf16* __restrict__ Bc,
                                                     bf16* __restrict__ Cc,
                                                     float* __restrict__ dtr){
    extern __shared__ short lds[];
    int wg = (blockIdx.x & 7)*84 + (blockIdx.x >> 3);   // 672 blocks, XCD swizzle
    size_t bm = (size_t)(wg / 21) * 256;
    size_t bn = (size_t)(wg % 21) * 256;
    f32x4 acc[8][4] = {};
    gemm_ring4<8>(A, B, D_MODEL, bm, bn, lds, acc);
    const int lane = threadIdx.x & 63;
    const int wid = threadIdx.x >> 6;
    const int wm = wid >> 2, wn = wid & 3;
    int cr = (lane >> 4)*4, cc = lane & 15;
    #pragma unroll
    for (int m = 0; m < 8; m++){
        size_t r0 = bm + wm*128 + m*16 + cr;
        #pragma unroll
        for (int n = 0; n < 4; n++){
            int c = (int)bn + wn*64 + n*16 + cc;
            #pragma unroll
            for (int j = 0; j < 4; j++){
                float v = acc[m][n][j];
                size_t r = r0 + j;
                if (c < O1)            z  [r * D_INNER + c]        = f2b(v);
                else if (c < O2)       xp [r * D_INNER + (c - O1)] = f2b(v);
                else if (c < O3)       Bc [r * 512 + (c - O2)]     = f2b(v);
                else if (c < O4)       Cc [r * 512 + (c - O3)]     = f2b(v);
                else if (c < PROJ_N)   dtr[r * 8 + (c - O4)]       = v;
            }
        }
    }
}

// ---------------- GEMM2: yn[8192x2048] x W_out[1024x2048]^T + hidden -> f32 ----------------
__global__ __launch_bounds__(512, 2) void k_gemm2_r4(const bf16* __restrict__ A,
                                                     const bf16* __restrict__ B,
                                                     const float* __restrict__ res,
                                                     float* __restrict__ C){
    extern __shared__ short lds[];
    int wg = (blockIdx.x & 7)*32 + (blockIdx.x >> 3);   // 256 blocks
    size_t bm = (size_t)(wg >> 2) * 128;
    size_t bn = (size_t)(wg & 3) * 256;
    f32x4 acc[4][4] = {};
    gemm_ring4<4>(A, B, D_INNER, bm, bn, lds, acc);
    const int lane = threadIdx.x & 63;
    const int wid = threadIdx.x >> 6;
    const int wm = wid >> 2, wn = wid & 3;
    int cr = (lane >> 4)*4, cc = lane & 15;
    #pragma unroll
    for (int m = 0; m < 4; m++){
        size_t r0 = bm + wm*64 + m*16 + cr;
        #pragma unroll
        for (int n = 0; n < 4; n++){
            size_t c = bn + wn*64 + n*16 + cc;
            #pragma unroll
            for (int j = 0; j < 4; j++){
                size_t r = r0 + j;
                C[r * D_MODEL + c] = acc[m][n][j] + res[r * D_MODEL + c];
            }
        }
    }
}

// ---------------- depthwise causal conv(4) + SiLU ----------------
__global__ __launch_bounds__(256) void k_conv_silu(const bf16* __restrict__ xp,
                                                   const float* __restrict__ cw,
                                                   const float* __restrict__ cb,
                                                   bf16* __restrict__ xout){
    int b = blockIdx.x;
    int c = blockIdx.y * 256 + threadIdx.x;
    float w0 = cw[c*4+0], w1 = cw[c*4+1], w2 = cw[c*4+2], w3 = cw[c*4+3];
    float bias = cb[c];
    const bf16* ib = xp + (size_t)b * SEQ * D_INNER + c;
    bf16* ob = xout + (size_t)b * SEQ * D_INNER + c;
    float x0 = 0.f, x1 = 0.f, x2 = 0.f;
    for (int s = 0; s < SEQ; s++){
        float x3 = b2f(ib[(size_t)s * D_INNER]);
        float a = x0*w0 + x1*w1 + x2*w2 + x3*w3 + bias;
        ob[(size_t)s * D_INNER] = f2b(silu_f(a));
        x0 = x1; x1 = x2; x2 = x3;
    }
}

// ---------------- precompute Wm (8x8), bm (8), A (8) ----------------
__global__ __launch_bounds__(64) void k_prep(const float* __restrict__ W_dt,
                                             const float* __restrict__ b_dt,
                                             const float* __restrict__ A_log,
                                             float* __restrict__ misc){
    int t = threadIdx.x;
    int h = t >> 3, k = t & 7;
    float s = 0.f;
    for (int d = 0; d < HEAD_DIM; d++) s += W_dt[(size_t)(h*HEAD_DIM + d) * N_HEADS + k];
    misc[t] = s * (1.0f/(float)HEAD_DIM);
    if (t < 8){
        float sb = 0.f;
        for (int d = 0; d < HEAD_DIM; d++) sb += b_dt[t*HEAD_DIM + d];
        misc[64 + t] = sb * (1.0f/(float)HEAD_DIM);
        misc[72 + t] = -expf(A_log[t]);
    }
}

// ---------------- dt_h -> logA cumsum (lcs) + tdec ----------------
__global__ __launch_bounds__(64) void k_dt_lcs(const float* __restrict__ dtr,
                                               const float* __restrict__ misc,
                                               float* __restrict__ lcs,
                                               float* __restrict__ tdec){
    __shared__ float sm[80];
    __shared__ float la[CHUNK][N_HEADS];
    int bc = blockIdx.x;
    int l = threadIdx.x;
    for (int i = l; i < 80; i += 64) sm[i] = misc[i];
    __syncthreads();
    const float* dr = dtr + (size_t)(bc*CHUNK + l) * 8;
    float d0 = dr[0], d1 = dr[1], d2 = dr[2], d3 = dr[3];
    float d4 = dr[4], d5 = dr[5], d6 = dr[6], d7 = dr[7];
    #pragma unroll
    for (int h = 0; h < 8; h++){
        float dt = sm[64+h]
                 + d0*sm[h*8+0] + d1*sm[h*8+1] + d2*sm[h*8+2] + d3*sm[h*8+3]
                 + d4*sm[h*8+4] + d5*sm[h*8+5] + d6*sm[h*8+6] + d7*sm[h*8+7];
        float sp = (dt > 20.f) ? dt : log1pf(expf(dt));
        la[l][h] = sp * sm[72+h];
    }
    __syncthreads();
    float out[8];
    #pragma unroll
    for (int h = 0; h < 8; h++) out[h] = 0.f;
    for (int l2 = 0; l2 <= l; l2++){
        #pragma unroll
        for (int h = 0; h < 8; h++) out[h] += la[l2][h];
    }
    float* lo = lcs + (size_t)(bc*CHUNK + l) * N_HEADS;
    #pragma unroll
    for (int h = 0; h < 8; h++) lo[h] = out[h];
    if (l == 63){
        #pragma unroll
        for (int h = 0; h < 8; h++) tdec[bc*N_HEADS + h] = expf(out[h]);
    }
}

// ================= fused chunked SSM (round-4, verified) =================
#define LB   0
#define LC   4096
#define LGM  8192
#define LXT  12800
#define LSH  29184
#define LF   45568
#define LDS_BYTES 91904

__device__ __forceinline__ short8 frag_sw(const short* arr, int r, int k){
    return *(const short8*)(arr + r*64 + (k ^ ((r&7)<<3)));
}

__global__ __launch_bounds__(256, 1) void k_ssm(const bf16* __restrict__ Bc,
                                                const bf16* __restrict__ Cc,
                                                bf16* xg,
                                                const float* __restrict__ lcs,
                                                const float* __restrict__ tdec,
                                                const float* __restrict__ Dv){
    extern __shared__ short lds[];
    short* Blds  = lds + LB;
    short* Clds  = lds + LC;
    short* GMlds = lds + LGM;
    short* XTlds = lds + LXT;
    short* Shr   = lds + LSH;
    float* el = (float*)(lds + LF);
    float* ml = el + 64;
    float* ee = el + 128;

    const int tid = threadIdx.x;
    const int lane = tid & 63;
    const int wid = tid >> 6;
    const int fr = lane & 15;
    const int fk = (lane >> 4) * 8;
    const int r0 = (lane >> 4) * 4;
    const int b = blockIdx.x >> 3, h = blockIdx.x & 7;
    const float Dh = Dv[h];

    f32x4 carry[4][4] = {};

    for (int c = 0; c < NCHUNK; c++){
        const int bc = b*NCHUNK + c;
        __syncthreads();
        #pragma unroll
        for (int i = 0; i < 2; i++){
            int slot = i*256 + tid;
            int s = slot >> 3, u = slot & 7;
            size_t rb = (size_t)(bc*CHUNK + s) * 512 + h*64 + ((u ^ (s&7)) * 8);
            gl16(Bc + rb, Blds + slot*8);
            gl16(Cc + rb, Clds + slot*8);
        }
        #pragma unroll
        for (int i = 0; i < 8; i++){
            int slot = i*256 + tid;
            int s = slot >> 5, ck = slot & 31;
            gl16(xg + (size_t)(bc*CHUNK + s) * D_INNER + h*HEAD_DIM + ck*8, Shr + slot*8);
        }
        if (tid < 64) el[tid] = lcs[(size_t)(bc*CHUNK + tid) * N_HEADS + h];
        __syncthreads();
        if (tid < 64){
            float e63 = el[63];
            ml[tid] = expf(e63 - el[tid]);
            ee[tid] = expf(el[tid]);
        }
        #pragma unroll
        for (int i = 0; i < 8; i++){
            short8 t8;
            #pragma unroll
            for (int j = 0; j < 8; j++) t8[j] = Shr[(i*8 + j)*HEAD_DIM + tid];
            *(short8*)(XTlds + tid*64 + ((i*8) ^ ((tid&7)<<3))) = t8;
        }
        __syncthreads();
        {
            f32x4 accg[4] = {};
            #pragma unroll
            for (int kk = 0; kk < 2; kk++){
                short8 a = frag_sw(Clds, wid*16 + fr, kk*32 + fk);
                #pragma unroll
                for (int nt = 0; nt < 4; nt++){
                    short8 bb = frag_sw(Blds, nt*16 + fr, kk*32 + fk);
                    accg[nt] = __builtin_amdgcn_mfma_f32_16x16x32_bf16(a, bb, accg[nt], 0, 0, 0);
                }
            }
            #pragma unroll
            for (int nt = 0; nt < 4; nt++){
                int s = nt*16 + fr;
                float els = el[s];
                #pragma unroll
                for (int j = 0; j < 4; j++){
                    int l = wid*16 + r0 + j;
                    float f = (s <= l) ? expf(el[l] - els) : 0.f;
                    GMlds[l*72 + s] = f2s(accg[nt][j] * f);
                }
            }
            int crow = wid*16 + (lane >> 2), cq = lane & 3;
            float fe = ee[crow];
            #pragma unroll
            for (int half = 0; half < 2; half++){
                short8 v = *(short8*)(Clds + crow*64 + cq*16 + half*8);
                #pragma unroll
                for (int j = 0; j < 8; j++) v[j] = f2s(s2f(v[j]) * fe);
                *(short8*)(Clds + crow*64 + cq*16 + half*8) = v;
            }
        }
        #pragma unroll
        for (int mt = 0; mt < 4; mt++)
            #pragma unroll
            for (int nt = 0; nt < 4; nt++)
                #pragma unroll
                for (int j = 0; j < 4; j++){
                    int d = wid*64 + mt*16 + r0 + j;
                    int n = nt*16 + fr;
                    Shr[d*64 + (n ^ ((d&7)<<3))] = f2s(carry[mt][nt][j]);
                }
        float btv[16];
        {
            int bn_ = tid & 63, bq = tid >> 6;
            #pragma unroll
            for (int i = 0; i < 16; i++){
                int s = bq*16 + i;
                btv[i] = s2f(Blds[s*64 + (bn_ ^ ((s&7)<<3))]) * ml[s];
            }
        }
        __syncthreads();
        {
            int bn_ = tid & 63, bq = tid >> 6;
            #pragma unroll
            for (int i = 0; i < 16; i++){
                int s = bq*16 + i;
                Blds[bn_*64 + (s ^ ((bn_&7)<<3))] = f2s(btv[i]);
            }
        }
        {
            f32x4 accy[4][4] = {};
            #pragma unroll
            for (int kk = 0; kk < 2; kk++){
                short8 ag[4], ae[4], bx[4], bh[4];
                #pragma unroll
                for (int mt = 0; mt < 4; mt++){
                    ag[mt] = *(const short8*)(GMlds + (mt*16 + fr)*72 + kk*32 + fk);
                    ae[mt] = frag_sw(Clds, mt*16 + fr, kk*32 + fk);
                }
                #pragma unroll
                for (int nt = 0; nt < 4; nt++){
                    int d = wid*64 + nt*16 + fr;
                    bx[nt] = frag_sw(XTlds, d, kk*32 + fk);
                    bh[nt] = frag_sw(Shr,  d, kk*32 + fk);
                }
                #pragma unroll
                for (int mt = 0; mt < 4; mt++)
                    #pragma unroll
                    for (int nt = 0; nt < 4; nt++){
                        accy[mt][nt] = __builtin_amdgcn_mfma_f32_16x16x32_bf16(ag[mt], bx[nt], accy[mt][nt], 0, 0, 0);
                        accy[mt][nt] = __builtin_amdgcn_mfma_f32_16x16x32_bf16(ae[mt], bh[nt], accy[mt][nt], 0, 0, 0);
                    }
            }
            #pragma unroll
            for (int mt = 0; mt < 4; mt++)
                #pragma unroll
                for (int nt = 0; nt < 4; nt++){
                    int d = wid*64 + nt*16 + fr;
                    #pragma unroll
                    for (int j = 0; j < 4; j++){
                        int l = mt*16 + r0 + j;
                        float xv = s2f(XTlds[d*64 + (l ^ ((d&7)<<3))]);
                        xg[(size_t)(bc*CHUNK + l) * D_INNER + h*HEAD_DIM + d] = f2b(accy[mt][nt][j] + xv*Dh);
                    }
                }
        }
        __syncthreads();
        {
            f32x4 accs[4][4] = {};
            #pragma unroll
            for (int kk = 0; kk < 2; kk++){
                short8 ax[4], bt[4];
                #pragma unroll
                for (int mt = 0; mt < 4; mt++)
                    ax[mt] = frag_sw(XTlds, wid*64 + mt*16 + fr, kk*32 + fk);
                #pragma unroll
                for (int nt = 0; nt < 4; nt++)
                    bt[nt] = frag_sw(Blds, nt*16 + fr, kk*32 + fk);
                #pragma unroll
                for (int mt = 0; mt < 4; mt++)
                    #pragma unroll
                    for (int nt = 0; nt < 4; nt++)
                        accs[mt][nt] = __builtin_amdgcn_mfma_f32_16x16x32_bf16(ax[mt], bt[nt], accs[mt][nt], 0, 0, 0);
            }
            float td = tdec[bc*N_HEADS + h];
            #pragma unroll
            for (int mt = 0; mt < 4; mt++)
                #pragma unroll
                for (int nt = 0; nt < 4; nt++)
                    carry[mt][nt] = td * carry[mt][nt] + accs[mt][nt];
        }
    }
}

// ---------------- gate with silu(z) + RMSNorm (output) -> yn bf16 ----------------
__global__ __launch_bounds__(256) void k_gate_rms(const bf16* __restrict__ y,
                                                  const bf16* __restrict__ z,
                                                  const float* __restrict__ g,
                                                  bf16* __restrict__ yn){
    int row = blockIdx.x, t = threadIdx.x;
    union { uint4 u; bf16 b[8]; } yv, zv, ov;
    yv.u = ((const uint4*)(y + (size_t)row * D_INNER))[t];
    zv.u = ((const uint4*)(z + (size_t)row * D_INNER))[t];
    float v[8];
    float ss = 0.f;
    #pragma unroll
    for (int i = 0; i < 8; i++){
        float a = b2f(yv.b[i]);
        float q = b2f(zv.b[i]);
        v[i] = a * silu_f(q);
        ss += v[i]*v[i];
    }
    ss = block_sum_256(ss);
    float sc = rsqrtf(ss * (1.0f/(float)D_INNER) + EPSF);
    const float4* g4 = (const float4*)g;
    float4 ga = g4[2*t], gb = g4[2*t+1];
    float gg[8] = {ga.x,ga.y,ga.z,ga.w,gb.x,gb.y,gb.z,gb.w};
    #pragma unroll
    for (int i = 0; i < 8; i++) ov.b[i] = f2b(v[i]*sc*gg[i]);
    ((uint4*)(yn + (size_t)row * D_INNER))[t] = ov.u;
}

extern "C" void kernel_launch(void* const* d_in, const int* in_sizes, int n_in,
                              void* d_out, int out_size, void* d_ws, size_t ws_size,
                              hipStream_t stream){
    const float* hidden = (const float*)d_in[0];
    const float* W_in   = (const float*)d_in[1];
    const float* conv_w = (const float*)d_in[2];
    const float* conv_b = (const float*)d_in[3];
    const float* W_dt   = (const float*)d_in[4];
    const float* b_dt   = (const float*)d_in[5];
    const float* A_log  = (const float*)d_in[6];
    const float* Dv     = (const float*)d_in[7];
    const float* W_out  = (const float*)d_in[8];
    const float* g_in   = (const float*)d_in[9];
    const float* g_out  = (const float*)d_in[10];

    // workspace layout (bytes) — total ~139.0 MiB
    char* ws = (char*)d_ws;
    bf16*  z    = (bf16*)(ws + 0);            // 33,554,432
    bf16*  xp   = (bf16*)(ws + 33554432);     // 33,554,432 (reused as yn)
    bf16*  x    = (bf16*)(ws + 67108864);     // 33,554,432 (y in place via k_ssm)
    bf16*  Bc   = (bf16*)(ws + 100663296);    //  8,388,608
    bf16*  Cc   = (bf16*)(ws + 109051904);    //  8,388,608
    float* dtr  = (float*)(ws + 117440512);   //    262,144
    float* lcs  = (float*)(ws + 117702656);   //    262,144
    float* tdec = (float*)(ws + 117964800);   //      4,096
    float* misc = (float*)(ws + 117968896);   //        512
    bf16*  Wb   = (bf16*)(ws + 117969408);    // 11,010,048 (W_in_b 5376x1024; later W_out_b)
    bf16*  hnb  = (bf16*)(ws + 128979456);    // 16,777,216
    bf16*  yn   = xp;

    k_rms_in<<<ROWS, 256, 0, stream>>>(hidden, g_in, hnb);
    k_cvt_pad<<<(PROJ_NPAD*D_MODEL/4 + 255)/256, 256, 0, stream>>>(W_in, Wb, PROJ_N*D_MODEL, PROJ_NPAD*D_MODEL);
    hipFuncSetAttribute((const void*)k_gemm1_r4, hipFuncAttributeMaxDynamicSharedMemorySize, 131072);
    k_gemm1_r4<<<(ROWS/256)*(PROJ_NPAD/256), 512, 131072, stream>>>(hnb, Wb, z, xp, Bc, Cc, dtr);
    k_conv_silu<<<dim3(BATCH, D_INNER/256), 256, 0, stream>>>(xp, conv_w, conv_b, x);
    k_prep<<<1, 64, 0, stream>>>(W_dt, b_dt, A_log, misc);
    k_dt_lcs<<<BATCH*NCHUNK, 64, 0, stream>>>(dtr, misc, lcs, tdec);
    hipFuncSetAttribute((const void*)k_ssm, hipFuncAttributeMaxDynamicSharedMemorySize, LDS_BYTES);
    k_ssm<<<BATCH*N_HEADS, 256, LDS_BYTES, stream>>>(Bc, Cc, x, lcs, tdec, Dv);
    k_gate_rms<<<ROWS, 256, 0, stream>>>(x, z, g_out, yn);
    k_cvt_pad<<<(D_MODEL*D_INNER/4 + 255)/256, 256, 0, stream>>>(W_out, Wb, D_MODEL*D_INNER, D_MODEL*D_INNER);
    hipFuncSetAttribute((const void*)k_gemm2_r4, hipFuncAttributeMaxDynamicSharedMemorySize, 98304);
    k_gemm2_r4<<<(ROWS/128)*(D_MODEL/256), 512, 98304, stream>>>(yn, Wb, hidden, (float*)d_out);
}

// Round 7
// 309.553 us; speedup vs baseline: 9.0675x; 1.1098x over previous
//
#include <hip/hip_runtime.h>
#include <hip/hip_bf16.h>
#include <math.h>

typedef __hip_bfloat16 bf16;
typedef __attribute__((ext_vector_type(8))) short short8;
typedef __attribute__((ext_vector_type(4))) float f32x4;

#define AS1 __attribute__((address_space(1)))
#define AS3 __attribute__((address_space(3)))

#define D_MODEL 1024
#define D_INNER 2048
#define N_HEADS 8
#define D_STATE 64
#define CHUNK 64
#define HEAD_DIM 256
#define NCHUNK 4
#define BATCH 32
#define SEQ 256
#define ROWS (BATCH*SEQ)          // 8192
#define PROJ_N 5128
#define PROJ_NPAD 5248            // 41 tiles of 128
#define O1 D_INNER                // 2048
#define O2 (2*D_INNER)            // 4096
#define O3 (O2 + N_HEADS*D_STATE) // 4608
#define O4 (O3 + N_HEADS*D_STATE) // 5120
#define EPSF 1.1920929e-07f

__device__ __forceinline__ float silu_f(float x){ return x / (1.0f + expf(-x)); }
__device__ __forceinline__ float b2f(bf16 v){ return __bfloat162float(v); }
__device__ __forceinline__ bf16  f2b(float v){ return __float2bfloat16(v); }
__device__ __forceinline__ short f2s(float v){ bf16 b = __float2bfloat16(v); union{bf16 b; short s;} u; u.b=b; return u.s; }
__device__ __forceinline__ float s2f(short v){ union{short s; bf16 b;} u; u.s=v; return __bfloat162float(u.b); }

__device__ __forceinline__ void gl16(const void* g, void* l){
    __builtin_amdgcn_global_load_lds((const AS1 void*)g, (AS3 void*)l, 16, 0, 0);
}

__device__ __forceinline__ float block_sum_256(float v){
    __shared__ float sm[4];
    #pragma unroll
    for (int o = 32; o > 0; o >>= 1) v += __shfl_down(v, o, 64);
    int lane = threadIdx.x & 63, w = threadIdx.x >> 6;
    if (lane == 0) sm[w] = v;
    __syncthreads();
    return sm[0] + sm[1] + sm[2] + sm[3];
}

// ---------------- RMSNorm (input) -> bf16 ----------------
__global__ __launch_bounds__(256) void k_rms_in(const float* __restrict__ x,
                                                const float* __restrict__ g,
                                                bf16* __restrict__ out){
    int row = blockIdx.x, t = threadIdx.x;
    const float4* xr = (const float4*)(x + (size_t)row * D_MODEL);
    float4 v = xr[t];
    float ss = v.x*v.x + v.y*v.y + v.z*v.z + v.w*v.w;
    ss = block_sum_256(ss);
    float sc = rsqrtf(ss * (1.0f/(float)D_MODEL) + EPSF);
    float4 gv = ((const float4*)g)[t];
    union { ushort4 u; bf16 b[4]; } o;
    o.b[0] = f2b(v.x*sc*gv.x); o.b[1] = f2b(v.y*sc*gv.y);
    o.b[2] = f2b(v.z*sc*gv.z); o.b[3] = f2b(v.w*sc*gv.w);
    ((ushort4*)(out + (size_t)row * D_MODEL))[t] = o.u;
}

// ---------------- f32 -> bf16 cast with zero-pad tail ----------------
__global__ __launch_bounds__(256) void k_cvt_pad(const float* __restrict__ in,
                                                 bf16* __restrict__ out,
                                                 int n_in, int n_out){
    int i = (blockIdx.x * 256 + threadIdx.x) * 4;
    if (i >= n_out) return;
    union { ushort4 u; bf16 b[4]; } o;
    if (i + 3 < n_in){
        float4 v = *(const float4*)(in + i);
        o.b[0]=f2b(v.x); o.b[1]=f2b(v.y); o.b[2]=f2b(v.z); o.b[3]=f2b(v.w);
    } else {
        #pragma unroll
        for (int j = 0; j < 4; j++) o.b[j] = f2b((i+j < n_in) ? in[i+j] : 0.f);
    }
    *(ushort4*)(out + i) = o.u;
}

// ================= ring-3 NT GEMM, 128x128 tile, 4 waves, BK=32 =================
// Superblock = 128 rows of A then 128 rows of B (256 global rows -> 128 srows).
// LDS slot (srow,s8) holds global (srow*2 + ((s8^(srow&7))>>2), kgrp (s8^(srow&7))&3).
// Ring of 3 x 16KB buffers; stage tile t+2 during tile t; vmcnt(4) per boundary
// (only last boundary drains to 0); ONE s_barrier per K-tile.

__device__ __forceinline__ short8 ld32(const short* base, int row, int g){
    int sr = row >> 1;
    int e8 = (((row & 1) << 2) | g) ^ (sr & 7);
    return *(const short8*)(base + sr*64 + e8*8);
}

__device__ __forceinline__ void stage_j(const bf16* __restrict__ Ag,
                                        const bf16* __restrict__ Bg,
                                        int K, size_t bm, size_t bn, int t,
                                        short* buf, int j){
    const int tid = threadIdx.x;
    const int wid = tid >> 6;
    int cidx = j*256 + tid;              // 0..1023 slot index
    int srow = cidx >> 3, s8 = cidx & 7;
    int eff = s8 ^ (srow & 7);
    int grow = srow*2 + (eff >> 2);      // 0..255
    int gcol = t*32 + (eff & 3)*8;
    const bf16* src = (grow < 128)
        ? Ag + (bm + grow) * (size_t)K + gcol
        : Bg + (bn + grow - 128) * (size_t)K + gcol;
    gl16(src, buf + (size_t)(j*256 + wid*64)*8);   // wave-uniform base + lane*16B
}

__device__ __forceinline__ void gemm_ring3(const bf16* __restrict__ Ag,
                                           const bf16* __restrict__ Bg,
                                           int K, size_t bm, size_t bn,
                                           short* lds, f32x4 (&acc)[4][4]){
    constexpr int TILE = 256*32;         // shorts per buffer (16 KB)
    const int NT = K >> 5;
    const int lane = threadIdx.x & 63;
    const int wid = threadIdx.x >> 6;
    const int wm = wid >> 1, wn = wid & 1;
    const int fr = lane & 15, g = lane >> 4;

    // prologue: stage tiles 0,1 (8 outstanding); tile0 resident -> vmcnt(4)
    #pragma unroll
    for (int j = 0; j < 4; j++) stage_j(Ag, Bg, K, bm, bn, 0, lds, j);
    #pragma unroll
    for (int j = 0; j < 4; j++) stage_j(Ag, Bg, K, bm, bn, 1, lds + TILE, j);
    asm volatile("s_waitcnt vmcnt(4)" ::: "memory");
    __builtin_amdgcn_sched_barrier(0);
    __builtin_amdgcn_s_barrier();
    __builtin_amdgcn_sched_barrier(0);

    int cur = 0;
    for (int t = 0; t < NT; t++){
        short* buf = lds + cur*TILE;
        int stgi = cur + 2; if (stgi >= 3) stgi -= 3;
        short* stg = lds + stgi*TILE;
        // ds_read fragments for this tile
        short8 a[4], b[4];
        #pragma unroll
        for (int m = 0; m < 4; m++) a[m] = ld32(buf, wm*64 + m*16 + fr, g);
        #pragma unroll
        for (int n = 0; n < 4; n++) b[n] = ld32(buf, 128 + wn*64 + n*16 + fr, g);
        // issue next+1 tile staging (hides ds latency under vmem issue + MFMA)
        if (t + 2 < NT){
            #pragma unroll
            for (int j = 0; j < 4; j++) stage_j(Ag, Bg, K, bm, bn, t+2, stg, j);
        }
        __builtin_amdgcn_s_setprio(1);
        #pragma unroll
        for (int m = 0; m < 4; m++)
            #pragma unroll
            for (int n = 0; n < 4; n++)
                acc[m][n] = __builtin_amdgcn_mfma_f32_16x16x32_bf16(a[m], b[n], acc[m][n], 0, 0, 0);
        __builtin_amdgcn_s_setprio(0);
        __builtin_amdgcn_sched_barrier(0);
        if (t + 2 < NT)      asm volatile("s_waitcnt vmcnt(4)" ::: "memory");
        else if (t + 1 < NT) asm volatile("s_waitcnt vmcnt(0)" ::: "memory");
        __builtin_amdgcn_sched_barrier(0);
        __builtin_amdgcn_s_barrier();     // buf[t] reads done by all; buf[t+1] resident
        __builtin_amdgcn_sched_barrier(0);
        cur = cur + 1 == 3 ? 0 : cur + 1;
    }
}

// ---------------- GEMM1: hn[8192x1024] x W_in[5248x1024]^T, segmented epilogue ----------------
__global__ __launch_bounds__(256, 3) void k_gemm1_r3(const bf16* __restrict__ A,
                                                     const bf16* __restrict__ B,
                                                     bf16* __restrict__ z,
                                                     bf16* __restrict__ xp,
                                                     bf16* __restrict__ Bc,
                                                     bf16* __restrict__ Cc,
                                                     float* __restrict__ dtr){
    extern __shared__ short lds[];
    int wg = (blockIdx.x & 7)*328 + (blockIdx.x >> 3);   // 2624 = 8*328, bijective
    size_t bm = (size_t)(wg / 41) * 128;
    size_t bn = (size_t)(wg % 41) * 128;
    f32x4 acc[4][4] = {};
    gemm_ring3(A, B, D_MODEL, bm, bn, lds, acc);
    const int lane = threadIdx.x & 63;
    const int wid = threadIdx.x >> 6;
    const int wm = wid >> 1, wn = wid & 1;
    int cr = (lane >> 4)*4, cc = lane & 15;
    #pragma unroll
    for (int m = 0; m < 4; m++){
        size_t r0 = bm + wm*64 + m*16 + cr;
        #pragma unroll
        for (int n = 0; n < 4; n++){
            int c = (int)bn + wn*64 + n*16 + cc;
            #pragma unroll
            for (int j = 0; j < 4; j++){
                float v = acc[m][n][j];
                size_t r = r0 + j;
                if (c < O1)            z  [r * D_INNER + c]        = f2b(v);
                else if (c < O2)       xp [r * D_INNER + (c - O1)] = f2b(v);
                else if (c < O3)       Bc [r * 512 + (c - O2)]     = f2b(v);
                else if (c < O4)       Cc [r * 512 + (c - O3)]     = f2b(v);
                else if (c < PROJ_N)   dtr[r * 8 + (c - O4)]       = v;
            }
        }
    }
}

// ---------------- GEMM2: yn[8192x2048] x W_out[1024x2048]^T + hidden -> f32 ----------------
__global__ __launch_bounds__(256, 3) void k_gemm2_r3(const bf16* __restrict__ A,
                                                     const bf16* __restrict__ B,
                                                     const float* __restrict__ res,
                                                     float* __restrict__ C){
    extern __shared__ short lds[];
    int wg = (blockIdx.x & 7)*64 + (blockIdx.x >> 3);    // 512 = 8*64, bijective
    size_t bm = (size_t)(wg >> 3) * 128;
    size_t bn = (size_t)(wg & 7) * 128;
    f32x4 acc[4][4] = {};
    gemm_ring3(A, B, D_INNER, bm, bn, lds, acc);
    const int lane = threadIdx.x & 63;
    const int wid = threadIdx.x >> 6;
    const int wm = wid >> 1, wn = wid & 1;
    int cr = (lane >> 4)*4, cc = lane & 15;
    #pragma unroll
    for (int m = 0; m < 4; m++){
        size_t r0 = bm + wm*64 + m*16 + cr;
        #pragma unroll
        for (int n = 0; n < 4; n++){
            size_t c = bn + wn*64 + n*16 + cc;
            #pragma unroll
            for (int j = 0; j < 4; j++){
                size_t r = r0 + j;
                C[r * D_MODEL + c] = acc[m][n][j] + res[r * D_MODEL + c];
            }
        }
    }
}

// ---------------- depthwise causal conv(4) + SiLU ----------------
__global__ __launch_bounds__(256) void k_conv_silu(const bf16* __restrict__ xp,
                                                   const float* __restrict__ cw,
                                                   const float* __restrict__ cb,
                                                   bf16* __restrict__ xout){
    int b = blockIdx.x;
    int c = blockIdx.y * 256 + threadIdx.x;
    float w0 = cw[c*4+0], w1 = cw[c*4+1], w2 = cw[c*4+2], w3 = cw[c*4+3];
    float bias = cb[c];
    const bf16* ib = xp + (size_t)b * SEQ * D_INNER + c;
    bf16* ob = xout + (size_t)b * SEQ * D_INNER + c;
    float x0 = 0.f, x1 = 0.f, x2 = 0.f;
    for (int s = 0; s < SEQ; s++){
        float x3 = b2f(ib[(size_t)s * D_INNER]);
        float a = x0*w0 + x1*w1 + x2*w2 + x3*w3 + bias;
        ob[(size_t)s * D_INNER] = f2b(silu_f(a));
        x0 = x1; x1 = x2; x2 = x3;
    }
}

// ---------------- precompute Wm (8x8), bm (8), A (8) ----------------
__global__ __launch_bounds__(64) void k_prep(const float* __restrict__ W_dt,
                                             const float* __restrict__ b_dt,
                                             const float* __restrict__ A_log,
                                             float* __restrict__ misc){
    int t = threadIdx.x;
    int h = t >> 3, k = t & 7;
    float s = 0.f;
    for (int d = 0; d < HEAD_DIM; d++) s += W_dt[(size_t)(h*HEAD_DIM + d) * N_HEADS + k];
    misc[t] = s * (1.0f/(float)HEAD_DIM);
    if (t < 8){
        float sb = 0.f;
        for (int d = 0; d < HEAD_DIM; d++) sb += b_dt[t*HEAD_DIM + d];
        misc[64 + t] = sb * (1.0f/(float)HEAD_DIM);
        misc[72 + t] = -expf(A_log[t]);
    }
}

// ---------------- dt_h -> logA cumsum (lcs) + tdec ----------------
__global__ __launch_bounds__(64) void k_dt_lcs(const float* __restrict__ dtr,
                                               const float* __restrict__ misc,
                                               float* __restrict__ lcs,
                                               float* __restrict__ tdec){
    __shared__ float sm[80];
    __shared__ float la[CHUNK][N_HEADS];
    int bc = blockIdx.x;
    int l = threadIdx.x;
    for (int i = l; i < 80; i += 64) sm[i] = misc[i];
    __syncthreads();
    const float* dr = dtr + (size_t)(bc*CHUNK + l) * 8;
    float d0 = dr[0], d1 = dr[1], d2 = dr[2], d3 = dr[3];
    float d4 = dr[4], d5 = dr[5], d6 = dr[6], d7 = dr[7];
    #pragma unroll
    for (int h = 0; h < 8; h++){
        float dt = sm[64+h]
                 + d0*sm[h*8+0] + d1*sm[h*8+1] + d2*sm[h*8+2] + d3*sm[h*8+3]
                 + d4*sm[h*8+4] + d5*sm[h*8+5] + d6*sm[h*8+6] + d7*sm[h*8+7];
        float sp = (dt > 20.f) ? dt : log1pf(expf(dt));
        la[l][h] = sp * sm[72+h];
    }
    __syncthreads();
    float out[8];
    #pragma unroll
    for (int h = 0; h < 8; h++) out[h] = 0.f;
    for (int l2 = 0; l2 <= l; l2++){
        #pragma unroll
        for (int h = 0; h < 8; h++) out[h] += la[l2][h];
    }
    float* lo = lcs + (size_t)(bc*CHUNK + l) * N_HEADS;
    #pragma unroll
    for (int h = 0; h < 8; h++) lo[h] = out[h];
    if (l == 63){
        #pragma unroll
        for (int h = 0; h < 8; h++) tdec[bc*N_HEADS + h] = expf(out[h]);
    }
}

// ================= fused chunked SSM (round-4, verified) =================
#define LB   0
#define LC   4096
#define LGM  8192
#define LXT  12800
#define LSH  29184
#define LF   45568
#define LDS_BYTES 91904

__device__ __forceinline__ short8 frag_sw(const short* arr, int r, int k){
    return *(const short8*)(arr + r*64 + (k ^ ((r&7)<<3)));
}

__global__ __launch_bounds__(256, 1) void k_ssm(const bf16* __restrict__ Bc,
                                                const bf16* __restrict__ Cc,
                                                bf16* xg,
                                                const float* __restrict__ lcs,
                                                const float* __restrict__ tdec,
                                                const float* __restrict__ Dv){
    extern __shared__ short lds[];
    short* Blds  = lds + LB;
    short* Clds  = lds + LC;
    short* GMlds = lds + LGM;
    short* XTlds = lds + LXT;
    short* Shr   = lds + LSH;
    float* el = (float*)(lds + LF);
    float* ml = el + 64;
    float* ee = el + 128;

    const int tid = threadIdx.x;
    const int lane = tid & 63;
    const int wid = tid >> 6;
    const int fr = lane & 15;
    const int fk = (lane >> 4) * 8;
    const int r0 = (lane >> 4) * 4;
    const int b = blockIdx.x >> 3, h = blockIdx.x & 7;
    const float Dh = Dv[h];

    f32x4 carry[4][4] = {};

    for (int c = 0; c < NCHUNK; c++){
        const int bc = b*NCHUNK + c;
        __syncthreads();
        #pragma unroll
        for (int i = 0; i < 2; i++){
            int slot = i*256 + tid;
            int s = slot >> 3, u = slot & 7;
            size_t rb = (size_t)(bc*CHUNK + s) * 512 + h*64 + ((u ^ (s&7)) * 8);
            gl16(Bc + rb, Blds + slot*8);
            gl16(Cc + rb, Clds + slot*8);
        }
        #pragma unroll
        for (int i = 0; i < 8; i++){
            int slot = i*256 + tid;
            int s = slot >> 5, ck = slot & 31;
            gl16(xg + (size_t)(bc*CHUNK + s) * D_INNER + h*HEAD_DIM + ck*8, Shr + slot*8);
        }
        if (tid < 64) el[tid] = lcs[(size_t)(bc*CHUNK + tid) * N_HEADS + h];
        __syncthreads();
        if (tid < 64){
            float e63 = el[63];
            ml[tid] = expf(e63 - el[tid]);
            ee[tid] = expf(el[tid]);
        }
        #pragma unroll
        for (int i = 0; i < 8; i++){
            short8 t8;
            #pragma unroll
            for (int j = 0; j < 8; j++) t8[j] = Shr[(i*8 + j)*HEAD_DIM + tid];
            *(short8*)(XTlds + tid*64 + ((i*8) ^ ((tid&7)<<3))) = t8;
        }
        __syncthreads();
        {
            f32x4 accg[4] = {};
            #pragma unroll
            for (int kk = 0; kk < 2; kk++){
                short8 a = frag_sw(Clds, wid*16 + fr, kk*32 + fk);
                #pragma unroll
                for (int nt = 0; nt < 4; nt++){
                    short8 bb = frag_sw(Blds, nt*16 + fr, kk*32 + fk);
                    accg[nt] = __builtin_amdgcn_mfma_f32_16x16x32_bf16(a, bb, accg[nt], 0, 0, 0);
                }
            }
            #pragma unroll
            for (int nt = 0; nt < 4; nt++){
                int s = nt*16 + fr;
                float els = el[s];
                #pragma unroll
                for (int j = 0; j < 4; j++){
                    int l = wid*16 + r0 + j;
                    float f = (s <= l) ? expf(el[l] - els) : 0.f;
                    GMlds[l*72 + s] = f2s(accg[nt][j] * f);
                }
            }
            int crow = wid*16 + (lane >> 2), cq = lane & 3;
            float fe = ee[crow];
            #pragma unroll
            for (int half = 0; half < 2; half++){
                short8 v = *(short8*)(Clds + crow*64 + cq*16 + half*8);
                #pragma unroll
                for (int j = 0; j < 8; j++) v[j] = f2s(s2f(v[j]) * fe);
                *(short8*)(Clds + crow*64 + cq*16 + half*8) = v;
            }
        }
        #pragma unroll
        for (int mt = 0; mt < 4; mt++)
            #pragma unroll
            for (int nt = 0; nt < 4; nt++)
                #pragma unroll
                for (int j = 0; j < 4; j++){
                    int d = wid*64 + mt*16 + r0 + j;
                    int n = nt*16 + fr;
                    Shr[d*64 + (n ^ ((d&7)<<3))] = f2s(carry[mt][nt][j]);
                }
        float btv[16];
        {
            int bn_ = tid & 63, bq = tid >> 6;
            #pragma unroll
            for (int i = 0; i < 16; i++){
                int s = bq*16 + i;
                btv[i] = s2f(Blds[s*64 + (bn_ ^ ((s&7)<<3))]) * ml[s];
            }
        }
        __syncthreads();
        {
            int bn_ = tid & 63, bq = tid >> 6;
            #pragma unroll
            for (int i = 0; i < 16; i++){
                int s = bq*16 + i;
                Blds[bn_*64 + (s ^ ((bn_&7)<<3))] = f2s(btv[i]);
            }
        }
        {
            f32x4 accy[4][4] = {};
            #pragma unroll
            for (int kk = 0; kk < 2; kk++){
                short8 ag[4], ae[4], bx[4], bh[4];
                #pragma unroll
                for (int mt = 0; mt < 4; mt++){
                    ag[mt] = *(const short8*)(GMlds + (mt*16 + fr)*72 + kk*32 + fk);
                    ae[mt] = frag_sw(Clds, mt*16 + fr, kk*32 + fk);
                }
                #pragma unroll
                for (int nt = 0; nt < 4; nt++){
                    int d = wid*64 + nt*16 + fr;
                    bx[nt] = frag_sw(XTlds, d, kk*32 + fk);
                    bh[nt] = frag_sw(Shr,  d, kk*32 + fk);
                }
                #pragma unroll
                for (int mt = 0; mt < 4; mt++)
                    #pragma unroll
                    for (int nt = 0; nt < 4; nt++){
                        accy[mt][nt] = __builtin_amdgcn_mfma_f32_16x16x32_bf16(ag[mt], bx[nt], accy[mt][nt], 0, 0, 0);
                        accy[mt][nt] = __builtin_amdgcn_mfma_f32_16x16x32_bf16(ae[mt], bh[nt], accy[mt][nt], 0, 0, 0);
                    }
            }
            #pragma unroll
            for (int mt = 0; mt < 4; mt++)
                #pragma unroll
                for (int nt = 0; nt < 4; nt++){
                    int d = wid*64 + nt*16 + fr;
                    #pragma unroll
                    for (int j = 0; j < 4; j++){
                        int l = mt*16 + r0 + j;
                        float xv = s2f(XTlds[d*64 + (l ^ ((d&7)<<3))]);
                        xg[(size_t)(bc*CHUNK + l) * D_INNER + h*HEAD_DIM + d] = f2b(accy[mt][nt][j] + xv*Dh);
                    }
                }
        }
        __syncthreads();
        {
            f32x4 accs[4][4] = {};
            #pragma unroll
            for (int kk = 0; kk < 2; kk++){
                short8 ax[4], bt[4];
                #pragma unroll
                for (int mt = 0; mt < 4; mt++)
                    ax[mt] = frag_sw(XTlds, wid*64 + mt*16 + fr, kk*32 + fk);
                #pragma unroll
                for (int nt = 0; nt < 4; nt++)
                    bt[nt] = frag_sw(Blds, nt*16 + fr, kk*32 + fk);
                #pragma unroll
                for (int mt = 0; mt < 4; mt++)
                    #pragma unroll
                    for (int nt = 0; nt < 4; nt++)
                        accs[mt][nt] = __builtin_amdgcn_mfma_f32_16x16x32_bf16(ax[mt], bt[nt], accs[mt][nt], 0, 0, 0);
            }
            float td = tdec[bc*N_HEADS + h];
            #pragma unroll
            for (int mt = 0; mt < 4; mt++)
                #pragma unroll
                for (int nt = 0; nt < 4; nt++)
                    carry[mt][nt] = td * carry[mt][nt] + accs[mt][nt];
        }
    }
}

// ---------------- gate with silu(z) + RMSNorm (output) -> yn bf16 ----------------
__global__ __launch_bounds__(256) void k_gate_rms(const bf16* __restrict__ y,
                                                  const bf16* __restrict__ z,
                                                  const float* __restrict__ g,
                                                  bf16* __restrict__ yn){
    int row = blockIdx.x, t = threadIdx.x;
    union { uint4 u; bf16 b[8]; } yv, zv, ov;
    yv.u = ((const uint4*)(y + (size_t)row * D_INNER))[t];
    zv.u = ((const uint4*)(z + (size_t)row * D_INNER))[t];
    float v[8];
    float ss = 0.f;
    #pragma unroll
    for (int i = 0; i < 8; i++){
        float a = b2f(yv.b[i]);
        float q = b2f(zv.b[i]);
        v[i] = a * silu_f(q);
        ss += v[i]*v[i];
    }
    ss = block_sum_256(ss);
    float sc = rsqrtf(ss * (1.0f/(float)D_INNER) + EPSF);
    const float4* g4 = (const float4*)g;
    float4 ga = g4[2*t], gb = g4[2*t+1];
    float gg[8] = {ga.x,ga.y,ga.z,ga.w,gb.x,gb.y,gb.z,gb.w};
    #pragma unroll
    for (int i = 0; i < 8; i++) ov.b[i] = f2b(v[i]*sc*gg[i]);
    ((uint4*)(yn + (size_t)row * D_INNER))[t] = ov.u;
}

extern "C" void kernel_launch(void* const* d_in, const int* in_sizes, int n_in,
                              void* d_out, int out_size, void* d_ws, size_t ws_size,
                              hipStream_t stream){
    const float* hidden = (const float*)d_in[0];
    const float* W_in   = (const float*)d_in[1];
    const float* conv_w = (const float*)d_in[2];
    const float* conv_b = (const float*)d_in[3];
    const float* W_dt   = (const float*)d_in[4];
    const float* b_dt   = (const float*)d_in[5];
    const float* A_log  = (const float*)d_in[6];
    const float* Dv     = (const float*)d_in[7];
    const float* W_out  = (const float*)d_in[8];
    const float* g_in   = (const float*)d_in[9];
    const float* g_out  = (const float*)d_in[10];

    // workspace layout (bytes) — total ~139.0 MiB
    char* ws = (char*)d_ws;
    bf16*  z    = (bf16*)(ws + 0);            // 33,554,432
    bf16*  xp   = (bf16*)(ws + 33554432);     // 33,554,432 (reused as yn)
    bf16*  x    = (bf16*)(ws + 67108864);     // 33,554,432 (y in place via k_ssm)
    bf16*  Bc   = (bf16*)(ws + 100663296);    //  8,388,608
    bf16*  Cc   = (bf16*)(ws + 109051904);    //  8,388,608
    float* dtr  = (float*)(ws + 117440512);   //    262,144
    float* lcs  = (float*)(ws + 117702656);   //    262,144
    float* tdec = (float*)(ws + 117964800);   //      4,096
    float* misc = (float*)(ws + 117968896);   //        512
    bf16*  Wb   = (bf16*)(ws + 117969408);    // 10,747,904 (W_in_b 5248x1024; later W_out_b)
    bf16*  hnb  = (bf16*)(ws + 128979456);    // 16,777,216
    bf16*  yn   = xp;

    k_rms_in<<<ROWS, 256, 0, stream>>>(hidden, g_in, hnb);
    k_cvt_pad<<<(PROJ_NPAD*D_MODEL/4 + 255)/256, 256, 0, stream>>>(W_in, Wb, PROJ_N*D_MODEL, PROJ_NPAD*D_MODEL);
    hipFuncSetAttribute((const void*)k_gemm1_r3, hipFuncAttributeMaxDynamicSharedMemorySize, 49152);
    k_gemm1_r3<<<(ROWS/128)*(PROJ_NPAD/128), 256, 49152, stream>>>(hnb, Wb, z, xp, Bc, Cc, dtr);
    k_conv_silu<<<dim3(BATCH, D_INNER/256), 256, 0, stream>>>(xp, conv_w, conv_b, x);
    k_prep<<<1, 64, 0, stream>>>(W_dt, b_dt, A_log, misc);
    k_dt_lcs<<<BATCH*NCHUNK, 64, 0, stream>>>(dtr, misc, lcs, tdec);
    hipFuncSetAttribute((const void*)k_ssm, hipFuncAttributeMaxDynamicSharedMemorySize, LDS_BYTES);
    k_ssm<<<BATCH*N_HEADS, 256, LDS_BYTES, stream>>>(Bc, Cc, x, lcs, tdec, Dv);
    k_gate_rms<<<ROWS, 256, 0, stream>>>(x, z, g_out, yn);
    k_cvt_pad<<<(D_MODEL*D_INNER/4 + 255)/256, 256, 0, stream>>>(W_out, Wb, D_MODEL*D_INNER, D_MODEL*D_INNER);
    hipFuncSetAttribute((const void*)k_gemm2_r3, hipFuncAttributeMaxDynamicSharedMemorySize, 49152);
    k_gemm2_r3<<<(ROWS/128)*(D_MODEL/128), 256, 49152, stream>>>(yn, Wb, hidden, (float*)d_out);
}